// Round 2
// baseline (9463.589 us; speedup 1.0000x reference)
//
#include <hip/hip_runtime.h>

// ---------------------------------------------------------------------------
// EpisodicMemoryModule: T=128, B=64, D=1024, 2 episodes.
// Decomposition:
//   - Feature GEMM z@W1^T split into 9 K-blocks; 4 episode-invariant blocks
//     (P0, K=4096) + 3 per-episode blocks (K=3072) + 2 rank-64 terms (addterm).
//   - Episode 0 reuses invariant feature buffer (m == q).
//   - att-GRU input gi = c@Wih^T batched over all t (GI, M=8192).
//   - Serial: 128 steps/episode of h@att_Whh^T (16-block MFMA kernel per step).
// All GEMMs bf16 operands, fp32 accumulate. h state fp32.
// WS budget: ~224 MiB (Zm aliases Zq; G stored bf16). Sentinel 12345.0 to
// d_out if ws_size is insufficient (diagnostic instead of a core dump).
// ---------------------------------------------------------------------------

typedef unsigned short u16;
typedef __attribute__((ext_vector_type(8))) short bf16x8;
typedef __attribute__((ext_vector_type(8))) unsigned short u16x8;
typedef __attribute__((ext_vector_type(4))) float f32x4;

__device__ inline float bf2f(u16 u) {
    union { unsigned u; float f; } v; v.u = ((unsigned)u) << 16; return v.f;
}
__device__ inline u16 f2bf(float f) {
    union { float f; unsigned u; } v; v.f = f;
    unsigned r = v.u + 0x7fff + ((v.u >> 16) & 1);
    return (u16)(r >> 16);
}
__device__ inline float sigf(float x) { return 1.f / (1.f + expf(-x)); }

__global__ void fill_sentinel(float* __restrict__ d, int n, float v) {
    for (int i = blockIdx.x * 256 + threadIdx.x; i < n; i += gridDim.x * 256) d[i] = v;
}

__global__ void zero_h(float* __restrict__ hf, u16* __restrict__ hb, int n) {
    for (int i = blockIdx.x * 256 + threadIdx.x; i < n; i += gridDim.x * 256) {
        hf[i] = 0.f; hb[i] = 0;
    }
}

// ---------------- generic elementwise converts ----------------
__global__ void conv_bf(const float* __restrict__ s, u16* __restrict__ d, int n) {
    for (int i = blockIdx.x * 256 + threadIdx.x; i < n; i += gridDim.x * 256)
        d[i] = f2bf(s[i]);
}

// Repack W1 [1024][9216] -> bf16 with K-block order {0,3,5,7, 4,6,8, 1, 2}
__global__ void repack_w1(const float* __restrict__ W1, u16* __restrict__ out) {
    const int jmap[9] = {0, 3, 5, 7, 4, 6, 8, 1, 2};
    const int total = 1024 * 9216;
    for (int i = blockIdx.x * 256 + threadIdx.x; i < total; i += gridDim.x * 256) {
        int n = i / 9216;
        int rest = i - n * 9216;
        int v = rest >> 10, k = rest & 1023;
        out[(size_t)n * 9216 + rest] = f2bf(W1[(size_t)n * 9216 + jmap[v] * 1024 + k]);
    }
}

// Zq[(t*64+b)][4096] = bf16{ c, c*q, |c-q|, c*Wbq }
__global__ void build_zq(const float* __restrict__ c, const float* __restrict__ q,
                         const float* __restrict__ wbq, u16* __restrict__ Zq) {
    const int total = 8192 * 1024;
    for (int i = blockIdx.x * 256 + threadIdx.x; i < total; i += gridDim.x * 256) {
        int row = i >> 10, k = i & 1023, b = row & 63;
        float cv = c[i];
        float qv = q[b * 1024 + k];
        float wv = wbq[b * 1024 + k];
        size_t ro = (size_t)row * 4096;
        Zq[ro + k]        = f2bf(cv);
        Zq[ro + 1024 + k] = f2bf(cv * qv);
        Zq[ro + 2048 + k] = f2bf(fabsf(cv - qv));
        Zq[ro + 3072 + k] = f2bf(cv * wv);
    }
}

// Zm[(t*64+b)][3072] = bf16{ c*m, |c-m|, c*Wbm }
__global__ void build_zm(const float* __restrict__ c, const float* __restrict__ m,
                         const float* __restrict__ wbm, u16* __restrict__ Zm) {
    const int total = 8192 * 1024;
    for (int i = blockIdx.x * 256 + threadIdx.x; i < total; i += gridDim.x * 256) {
        int row = i >> 10, k = i & 1023, b = row & 63;
        float cv = c[i];
        float mv = m[b * 1024 + k];
        float wv = wbm[b * 1024 + k];
        size_t ro = (size_t)row * 3072;
        Zm[ro + k]        = f2bf(cv * mv);
        Zm[ro + 1024 + k] = f2bf(fabsf(cv - mv));
        Zm[ro + 2048 + k] = f2bf(cv * wv);
    }
}

// ---------------- generic C = A @ B^T GEMM (bf16 in, fp32 acc) ----------------
// A: [M x K] bf16 row-major, lda. B: [N x K] bf16 row-major, ldb. Tile 128x128.
// MODE 0: fp32 out           1: fp32 out + bias[n]       2: bf16 out + bias[n]
//      3: fp32 out + prevf[m][n]
//      4: bf16 out = tanh(acc + prevf[m][n] + addb[m&63][n])
//      5: bf16 out = sigmoid(acc + bias[n])
template <int MODE>
__global__ __launch_bounds__(256) void gemm_bt(
    const u16* __restrict__ A, int lda,
    const u16* __restrict__ B, int ldb,
    void* __restrict__ C, int M, int N, int K,
    const float* __restrict__ bias,
    const float* __restrict__ prevf,
    const float* __restrict__ addb) {
    __shared__ u16 As[128 * 40];
    __shared__ u16 Bs[128 * 40];
    const int t = threadIdx.x;
    const int bn = blockIdx.x, bm = blockIdx.y;
    const int w = t >> 6, lane = t & 63, lr = lane & 15, quad = lane >> 4;
    const int wm = (w >> 1) * 64, wn = (w & 1) * 64;
    const int r0 = t >> 2, kb = (t & 3) * 8;

    f32x4 zero4 = {0.f, 0.f, 0.f, 0.f};
    f32x4 acc[4][4];
#pragma unroll
    for (int i = 0; i < 4; i++)
#pragma unroll
        for (int j = 0; j < 4; j++) acc[i][j] = zero4;

    const u16x8 zz = {0, 0, 0, 0, 0, 0, 0, 0};

    for (int k0 = 0; k0 < K; k0 += 32) {
#pragma unroll
        for (int rr = r0; rr < 128; rr += 64) {
            int gm = bm * 128 + rr;
            u16x8 av = zz;
            if (gm < M) av = *(const u16x8*)(A + (size_t)gm * lda + k0 + kb);
            *(u16x8*)(As + rr * 40 + kb) = av;
            int gn = bn * 128 + rr;
            *(u16x8*)(Bs + rr * 40 + kb) = *(const u16x8*)(B + (size_t)gn * ldb + k0 + kb);
        }
        __syncthreads();
        bf16x8 af[4], bfr[4];
#pragma unroll
        for (int i = 0; i < 4; i++) af[i] = *(const bf16x8*)(As + (wm + i * 16 + lr) * 40 + quad * 8);
#pragma unroll
        for (int j = 0; j < 4; j++) bfr[j] = *(const bf16x8*)(Bs + (wn + j * 16 + lr) * 40 + quad * 8);
#pragma unroll
        for (int i = 0; i < 4; i++)
#pragma unroll
            for (int j = 0; j < 4; j++)
                acc[i][j] = __builtin_amdgcn_mfma_f32_16x16x32_bf16(af[i], bfr[j], acc[i][j], 0, 0, 0);
        __syncthreads();
    }

#pragma unroll
    for (int i = 0; i < 4; i++) {
        int gm0 = bm * 128 + wm + i * 16 + quad * 4;
#pragma unroll
        for (int j = 0; j < 4; j++) {
            int gn = bn * 128 + wn + j * 16 + lr;
#pragma unroll
            for (int reg = 0; reg < 4; reg++) {
                int gm = gm0 + reg;
                if (gm >= M) continue;
                float v = acc[i][j][reg];
                size_t o = (size_t)gm * N + gn;
                if constexpr (MODE == 0) ((float*)C)[o] = v;
                else if constexpr (MODE == 1) ((float*)C)[o] = v + bias[gn];
                else if constexpr (MODE == 2) ((u16*)C)[o] = f2bf(v + bias[gn]);
                else if constexpr (MODE == 3) ((float*)C)[o] = v + prevf[o];
                else if constexpr (MODE == 4)
                    ((u16*)C)[o] = f2bf(tanhf(v + prevf[o] + addb[(size_t)(gm & 63) * N + gn]));
                else if constexpr (MODE == 5) ((u16*)C)[o] = f2bf(sigf(v + bias[gn]));
            }
        }
    }
}

// ---------------- one attention-GRU step ----------------
// 16 blocks; block owns d-slice [ds, ds+64). Wave w owns d in [ds+w*16, ds+w*16+16)
// across all 3 gates -> gate math stays in-register.
__global__ __launch_bounds__(256) void gru_step(
    const u16* __restrict__ hbf, const float* __restrict__ hf,
    const u16* __restrict__ Whh, const float* __restrict__ bhh,
    const u16* __restrict__ GIt, const u16* __restrict__ Gt,
    float* __restrict__ hf_out, u16* __restrict__ hbf_out) {
    __shared__ u16 hs[64 * 40];
    __shared__ u16 Ws[192 * 40];
    const int t = threadIdx.x;
    const int ds = blockIdx.x * 64;
    const int w = t >> 6, lane = t & 63, lr = lane & 15, quad = lane >> 4;
    const int r0 = t >> 2, kb = (t & 3) * 8;

    f32x4 zero4 = {0.f, 0.f, 0.f, 0.f};
    f32x4 acc[4][3];
#pragma unroll
    for (int i = 0; i < 4; i++)
#pragma unroll
        for (int g = 0; g < 3; g++) acc[i][g] = zero4;

    for (int k0 = 0; k0 < 1024; k0 += 32) {
        *(u16x8*)(hs + r0 * 40 + kb) = *(const u16x8*)(hbf + r0 * 1024 + k0 + kb);
#pragma unroll
        for (int ln = r0; ln < 192; ln += 64) {
            int g = ln >> 6, dl = ln & 63;
            *(u16x8*)(Ws + ln * 40 + kb) =
                *(const u16x8*)(Whh + (size_t)(g * 1024 + ds + dl) * 1024 + k0 + kb);
        }
        __syncthreads();
        bf16x8 af[4], bfr[3];
#pragma unroll
        for (int i = 0; i < 4; i++) af[i] = *(const bf16x8*)(hs + (i * 16 + lr) * 40 + quad * 8);
#pragma unroll
        for (int g = 0; g < 3; g++) bfr[g] = *(const bf16x8*)(Ws + (g * 64 + w * 16 + lr) * 40 + quad * 8);
#pragma unroll
        for (int i = 0; i < 4; i++)
#pragma unroll
            for (int g = 0; g < 3; g++)
                acc[i][g] = __builtin_amdgcn_mfma_f32_16x16x32_bf16(af[i], bfr[g], acc[i][g], 0, 0, 0);
        __syncthreads();
    }

    const int d = ds + w * 16 + lr;
    const float bhr = bhh[d], bhz = bhh[1024 + d], bhn = bhh[2048 + d];
#pragma unroll
    for (int i = 0; i < 4; i++) {
#pragma unroll
        for (int reg = 0; reg < 4; reg++) {
            int b = i * 16 + quad * 4 + reg;
            float ghr = acc[i][0][reg] + bhr;
            float ghz = acc[i][1][reg] + bhz;
            float ghn = acc[i][2][reg] + bhn;
            float gir = bf2f(GIt[b * 3072 + d]);
            float giz = bf2f(GIt[b * 3072 + 1024 + d]);
            float gin = bf2f(GIt[b * 3072 + 2048 + d]);
            float r = sigf(gir + ghr);
            float z = sigf(giz + ghz);
            float n = tanhf(gin + r * ghn);
            float ho = hf[b * 1024 + d];
            float hatt = (1.f - z) * n + z * ho;
            float g = bf2f(Gt[b * 1024 + d]);
            float hn = g * hatt + (1.f - g) * ho;
            hf_out[b * 1024 + d] = hn;
            hbf_out[b * 1024 + d] = f2bf(hn);
        }
    }
}

// ---------------- mem GRU cell: m' = GRUCell(e, m) ----------------
__global__ __launch_bounds__(256) void gru_mem(
    const u16* __restrict__ ebf, const u16* __restrict__ mbf,
    const float* __restrict__ mold,
    const u16* __restrict__ Wih, const u16* __restrict__ Whh,
    const float* __restrict__ bih, const float* __restrict__ bhh,
    float* __restrict__ mout, u16* __restrict__ mbf_out) {
    __shared__ u16 es[64 * 40];
    __shared__ u16 ms[64 * 40];
    __shared__ u16 Wi[192 * 40];
    __shared__ u16 Wh[192 * 40];
    const int t = threadIdx.x;
    const int ds = blockIdx.x * 64;
    const int w = t >> 6, lane = t & 63, lr = lane & 15, quad = lane >> 4;
    const int r0 = t >> 2, kb = (t & 3) * 8;

    f32x4 zero4 = {0.f, 0.f, 0.f, 0.f};
    f32x4 ai[4][3], ah[4][3];
#pragma unroll
    for (int i = 0; i < 4; i++)
#pragma unroll
        for (int g = 0; g < 3; g++) { ai[i][g] = zero4; ah[i][g] = zero4; }

    for (int k0 = 0; k0 < 1024; k0 += 32) {
        *(u16x8*)(es + r0 * 40 + kb) = *(const u16x8*)(ebf + r0 * 1024 + k0 + kb);
        *(u16x8*)(ms + r0 * 40 + kb) = *(const u16x8*)(mbf + r0 * 1024 + k0 + kb);
#pragma unroll
        for (int ln = r0; ln < 192; ln += 64) {
            int g = ln >> 6, dl = ln & 63;
            size_t ro = (size_t)(g * 1024 + ds + dl) * 1024 + k0 + kb;
            *(u16x8*)(Wi + ln * 40 + kb) = *(const u16x8*)(Wih + ro);
            *(u16x8*)(Wh + ln * 40 + kb) = *(const u16x8*)(Whh + ro);
        }
        __syncthreads();
        bf16x8 ae[4], am[4], bi[3], bh[3];
#pragma unroll
        for (int i = 0; i < 4; i++) {
            ae[i] = *(const bf16x8*)(es + (i * 16 + lr) * 40 + quad * 8);
            am[i] = *(const bf16x8*)(ms + (i * 16 + lr) * 40 + quad * 8);
        }
#pragma unroll
        for (int g = 0; g < 3; g++) {
            bi[g] = *(const bf16x8*)(Wi + (g * 64 + w * 16 + lr) * 40 + quad * 8);
            bh[g] = *(const bf16x8*)(Wh + (g * 64 + w * 16 + lr) * 40 + quad * 8);
        }
#pragma unroll
        for (int i = 0; i < 4; i++)
#pragma unroll
            for (int g = 0; g < 3; g++) {
                ai[i][g] = __builtin_amdgcn_mfma_f32_16x16x32_bf16(ae[i], bi[g], ai[i][g], 0, 0, 0);
                ah[i][g] = __builtin_amdgcn_mfma_f32_16x16x32_bf16(am[i], bh[g], ah[i][g], 0, 0, 0);
            }
        __syncthreads();
    }

    const int d = ds + w * 16 + lr;
    const float bir = bih[d], biz = bih[1024 + d], bin = bih[2048 + d];
    const float bhr = bhh[d], bhz = bhh[1024 + d], bhn = bhh[2048 + d];
#pragma unroll
    for (int i = 0; i < 4; i++) {
#pragma unroll
        for (int reg = 0; reg < 4; reg++) {
            int b = i * 16 + quad * 4 + reg;
            float r = sigf(ai[i][0][reg] + bir + ah[i][0][reg] + bhr);
            float z = sigf(ai[i][1][reg] + biz + ah[i][1][reg] + bhz);
            float n = tanhf(ai[i][2][reg] + bin + r * (ah[i][2][reg] + bhn));
            float mo = mold[b * 1024 + d];
            float mn = (1.f - z) * n + z * mo;
            mout[b * 1024 + d] = mn;
            mbf_out[b * 1024 + d] = f2bf(mn);
        }
    }
}

// ---------------------------------------------------------------------------
extern "C" void kernel_launch(void* const* d_in, const int* in_sizes, int n_in,
                              void* d_out, int out_size, void* d_ws, size_t ws_size,
                              hipStream_t stream) {
    const float* c    = (const float*)d_in[0];
    const float* q    = (const float*)d_in[1];
    const float* Wb   = (const float*)d_in[2];
    const float* W1   = (const float*)d_in[3];
    const float* W1b  = (const float*)d_in[4];
    const float* W2   = (const float*)d_in[5];
    const float* W2b  = (const float*)d_in[6];
    const float* mWih = (const float*)d_in[7];
    const float* mWhh = (const float*)d_in[8];
    const float* mbih = (const float*)d_in[9];
    const float* mbhh = (const float*)d_in[10];
    const float* aWih = (const float*)d_in[11];
    const float* aWhh = (const float*)d_in[12];
    const float* abih = (const float*)d_in[13];
    const float* abhh = (const float*)d_in[14];

    char* p = (char*)d_ws;
    auto nb = [&](size_t bytes) -> char* {
        char* r = p; p += (bytes + 255) & ~(size_t)255; return r;
    };
    u16* W1p     = (u16*)nb(1024ull * 9216 * 2);   // 18 MiB
    u16* Wb_bf   = (u16*)nb(1024ull * 1024 * 2);   //  2
    u16* W2_bf   = (u16*)nb(1024ull * 1024 * 2);   //  2
    u16* aWih_bf = (u16*)nb(3072ull * 1024 * 2);   //  6
    u16* aWhh_bf = (u16*)nb(3072ull * 1024 * 2);   //  6
    u16* mWih_bf = (u16*)nb(3072ull * 1024 * 2);   //  6
    u16* mWhh_bf = (u16*)nb(3072ull * 1024 * 2);   //  6
    u16* qbf     = (u16*)nb(64 * 1024 * 2);
    u16* m1bf    = (u16*)nb(64 * 1024 * 2);
    u16* m2bf    = (u16*)nb(64 * 1024 * 2);
    u16* hbf0    = (u16*)nb(64 * 1024 * 2);
    u16* hbf1    = (u16*)nb(64 * 1024 * 2);
    u16* Zq      = (u16*)nb(8192ull * 4096 * 2);   // 64 MiB (Zm aliases this)
    u16* GIb     = (u16*)nb(8192ull * 3072 * 2);   // 48 MiB
    u16* G1      = (u16*)nb(8192ull * 1024 * 2);   // 16 MiB
    u16* G       = (u16*)nb(8192ull * 1024 * 2);   // 16 MiB (bf16 gate)
    float* P0    = (float*)nb(8192ull * 1024 * 4); // 32 MiB
    float* Wbq   = (float*)nb(64 * 1024 * 4);
    float* Wbm   = (float*)nb(64 * 1024 * 4);
    float* addq  = (float*)nb(64 * 1024 * 4);
    float* addt  = (float*)nb(64 * 1024 * 4);
    float* h0    = (float*)nb(64 * 1024 * 4);
    float* h1    = (float*)nb(64 * 1024 * 4);
    float* m1    = (float*)nb(64 * 1024 * 4);
    u16* Zm      = Zq;  // alias: Zq dead once episode-0 G1 GEMM completes

    size_t needed = (size_t)(p - (char*)d_ws);
    if (needed > ws_size) {
        // Diagnostic: workspace too small -> unmistakable sentinel, no fault.
        fill_sentinel<<<256, 256, 0, stream>>>((float*)d_out, out_size, 12345.0f);
        return;
    }

    // weight converts
    conv_bf<<<256, 256, 0, stream>>>(q, qbf, 64 * 1024);
    conv_bf<<<2048, 256, 0, stream>>>(Wb, Wb_bf, 1024 * 1024);
    conv_bf<<<2048, 256, 0, stream>>>(W2, W2_bf, 1024 * 1024);
    conv_bf<<<4096, 256, 0, stream>>>(aWih, aWih_bf, 3072 * 1024);
    conv_bf<<<4096, 256, 0, stream>>>(aWhh, aWhh_bf, 3072 * 1024);
    conv_bf<<<4096, 256, 0, stream>>>(mWih, mWih_bf, 3072 * 1024);
    conv_bf<<<4096, 256, 0, stream>>>(mWhh, mWhh_bf, 3072 * 1024);
    repack_w1<<<8192, 256, 0, stream>>>(W1, W1p);

    // episode-invariant precompute
    gemm_bt<0><<<dim3(8, 1), 256, 0, stream>>>(qbf, 1024, Wb_bf, 1024, Wbq, 64, 1024, 1024,
                                               nullptr, nullptr, nullptr);
    gemm_bt<1><<<dim3(8, 1), 256, 0, stream>>>(qbf, 1024, W1p + 8192, 9216, addq, 64, 1024, 1024,
                                               W1b, nullptr, nullptr);
    build_zq<<<16384, 256, 0, stream>>>(c, q, Wbq, Zq);
    gemm_bt<0><<<dim3(8, 64), 256, 0, stream>>>(Zq, 4096, W1p, 9216, P0, 8192, 1024, 4096,
                                                nullptr, nullptr, nullptr);
    gemm_bt<2><<<dim3(24, 64), 256, 0, stream>>>(Zq, 4096, aWih_bf, 1024, GIb, 8192, 3072, 1024,
                                                 abih, nullptr, nullptr);

    for (int ep = 0; ep < 2; ep++) {
        const u16* mbf_cur = ep ? m1bf : qbf;
        const float* mold  = ep ? (const float*)m1 : q;
        // addterm = m@W1_blk1 + (q@W1_blk2 + b1)
        gemm_bt<3><<<dim3(8, 1), 256, 0, stream>>>(mbf_cur, 1024, W1p + 7168, 9216, addt,
                                                   64, 1024, 1024, nullptr, addq, nullptr);
        const u16* AG1; int ldaG1;
        if (ep) {
            gemm_bt<0><<<dim3(8, 1), 256, 0, stream>>>(m1bf, 1024, Wb_bf, 1024, Wbm,
                                                       64, 1024, 1024, nullptr, nullptr, nullptr);
            build_zm<<<16384, 256, 0, stream>>>(c, m1, Wbm, Zm);
            AG1 = Zm; ldaG1 = 3072;
        } else {
            AG1 = Zq + 1024; ldaG1 = 4096;  // m==q: reuse invariant features
        }
        gemm_bt<4><<<dim3(8, 64), 256, 0, stream>>>(AG1, ldaG1, W1p + 4096, 9216, G1,
                                                    8192, 1024, 3072, nullptr, P0, addt);
        gemm_bt<5><<<dim3(8, 64), 256, 0, stream>>>(G1, 1024, W2_bf, 1024, G,
                                                    8192, 1024, 1024, W2b, nullptr, nullptr);

        zero_h<<<256, 256, 0, stream>>>(h0, hbf0, 64 * 1024);
        for (int t = 0; t < 128; t++) {
            const u16* hbi = (t & 1) ? hbf1 : hbf0;
            const float* hfi = (t & 1) ? h1 : h0;
            float* hfo = (t & 1) ? h0 : h1;
            u16* hbo = (t & 1) ? hbf0 : hbf1;
            gru_step<<<16, 256, 0, stream>>>(hbi, hfi, aWhh_bf, abhh,
                                             GIb + (size_t)t * 64 * 3072,
                                             G + (size_t)t * 64 * 1024, hfo, hbo);
        }
        // 128 steps (even) -> final h in h0/hbf0
        float* mo = ep ? (float*)d_out : m1;
        u16* mob = ep ? m2bf : m1bf;
        gru_mem<<<16, 256, 0, stream>>>(hbf0, mbf_cur, mold, mWih_bf, mWhh_bf,
                                        mbih, mbhh, mo, mob);
    }
}

// Round 3
// 4819.373 us; speedup vs baseline: 1.9637x; 1.9637x over previous
//
#include <hip/hip_runtime.h>

// ---------------------------------------------------------------------------
// EpisodicMemoryModule: T=128, B=64, D=1024, 2 episodes.
//   - Feature GEMM z@W1^T split into 9 K-blocks; invariants hoisted (P0, K=4096),
//     per-episode blocks (K=3072), rank-64 terms folded into epilogue.
//   - Episode 0 reuses invariant features (m == q).
//   - att-GRU input gi = c@Wih^T batched over all t (GI, M=8192).
//   - Serial part: ONE persistent kernel per episode; 64 blocks × 16-d slice,
//     att_Whh slice LDS-resident (~97 KiB, dynamic LDS), h fp32 state in
//     registers, grid barrier via device-scope atomic counter per step.
// ---------------------------------------------------------------------------

typedef unsigned short u16;
typedef __attribute__((ext_vector_type(8))) short bf16x8;
typedef __attribute__((ext_vector_type(8))) unsigned short u16x8;
typedef __attribute__((ext_vector_type(4))) float f32x4;

__device__ inline float bf2f(u16 u) {
    union { unsigned u; float f; } v; v.u = ((unsigned)u) << 16; return v.f;
}
__device__ inline u16 f2bf(float f) {
    union { float f; unsigned u; } v; v.f = f;
    unsigned r = v.u + 0x7fff + ((v.u >> 16) & 1);
    return (u16)(r >> 16);
}
__device__ inline float sigf(float x) { return 1.f / (1.f + expf(-x)); }

__global__ void fill_sentinel(float* __restrict__ d, int n, float v) {
    for (int i = blockIdx.x * 256 + threadIdx.x; i < n; i += gridDim.x * 256) d[i] = v;
}

// zero h bf16 buffer + barrier counter (ws is re-poisoned before every call)
__global__ void zero_state(u16* __restrict__ hb, unsigned* __restrict__ bar, int n) {
    int i = blockIdx.x * 256 + threadIdx.x;
    if (i == 0) *bar = 0u;
    for (; i < n; i += gridDim.x * 256) hb[i] = 0;
}

// ---------------- elementwise converts ----------------
__global__ void conv_bf(const float* __restrict__ s, u16* __restrict__ d, int n) {
    for (int i = blockIdx.x * 256 + threadIdx.x; i < n; i += gridDim.x * 256)
        d[i] = f2bf(s[i]);
}

// Repack W1 [1024][9216] -> bf16 with K-block order {0,3,5,7, 4,6,8, 1, 2}
__global__ void repack_w1(const float* __restrict__ W1, u16* __restrict__ out) {
    const int jmap[9] = {0, 3, 5, 7, 4, 6, 8, 1, 2};
    const int total = 1024 * 9216;
    for (int i = blockIdx.x * 256 + threadIdx.x; i < total; i += gridDim.x * 256) {
        int n = i / 9216;
        int rest = i - n * 9216;
        int v = rest >> 10, k = rest & 1023;
        out[(size_t)n * 9216 + rest] = f2bf(W1[(size_t)n * 9216 + jmap[v] * 1024 + k]);
    }
}

// Zq[(t*64+b)][4096] = bf16{ c, c*q, |c-q|, c*Wbq }
__global__ void build_zq(const float* __restrict__ c, const float* __restrict__ q,
                         const float* __restrict__ wbq, u16* __restrict__ Zq) {
    const int total = 8192 * 1024;
    for (int i = blockIdx.x * 256 + threadIdx.x; i < total; i += gridDim.x * 256) {
        int row = i >> 10, k = i & 1023, b = row & 63;
        float cv = c[i];
        float qv = q[b * 1024 + k];
        float wv = wbq[b * 1024 + k];
        size_t ro = (size_t)row * 4096;
        Zq[ro + k]        = f2bf(cv);
        Zq[ro + 1024 + k] = f2bf(cv * qv);
        Zq[ro + 2048 + k] = f2bf(fabsf(cv - qv));
        Zq[ro + 3072 + k] = f2bf(cv * wv);
    }
}

// Zm[(t*64+b)][3072] = bf16{ c*m, |c-m|, c*Wbm }
__global__ void build_zm(const float* __restrict__ c, const float* __restrict__ m,
                         const float* __restrict__ wbm, u16* __restrict__ Zm) {
    const int total = 8192 * 1024;
    for (int i = blockIdx.x * 256 + threadIdx.x; i < total; i += gridDim.x * 256) {
        int row = i >> 10, k = i & 1023, b = row & 63;
        float cv = c[i];
        float mv = m[b * 1024 + k];
        float wv = wbm[b * 1024 + k];
        size_t ro = (size_t)row * 3072;
        Zm[ro + k]        = f2bf(cv * mv);
        Zm[ro + 1024 + k] = f2bf(fabsf(cv - mv));
        Zm[ro + 2048 + k] = f2bf(cv * wv);
    }
}

// ---------------- generic C = A @ B^T GEMM (bf16 in, fp32 acc) ----------------
// MODE 0: fp32 out           1: fp32 out + bias[n]       2: bf16 out + bias[n]
//      3: fp32 out + prevf[m][n]
//      4: bf16 out = tanh(acc + prevf[m][n] + addb[m&63][n])
//      5: bf16 out = sigmoid(acc + bias[n])
template <int MODE>
__global__ __launch_bounds__(256) void gemm_bt(
    const u16* __restrict__ A, int lda,
    const u16* __restrict__ B, int ldb,
    void* __restrict__ C, int M, int N, int K,
    const float* __restrict__ bias,
    const float* __restrict__ prevf,
    const float* __restrict__ addb) {
    __shared__ u16 As[128 * 40];
    __shared__ u16 Bs[128 * 40];
    const int t = threadIdx.x;
    const int bn = blockIdx.x, bm = blockIdx.y;
    const int w = t >> 6, lane = t & 63, lr = lane & 15, quad = lane >> 4;
    const int wm = (w >> 1) * 64, wn = (w & 1) * 64;
    const int r0 = t >> 2, kb = (t & 3) * 8;

    f32x4 zero4 = {0.f, 0.f, 0.f, 0.f};
    f32x4 acc[4][4];
#pragma unroll
    for (int i = 0; i < 4; i++)
#pragma unroll
        for (int j = 0; j < 4; j++) acc[i][j] = zero4;

    const u16x8 zz = {0, 0, 0, 0, 0, 0, 0, 0};

    for (int k0 = 0; k0 < K; k0 += 32) {
#pragma unroll
        for (int rr = r0; rr < 128; rr += 64) {
            int gm = bm * 128 + rr;
            u16x8 av = zz;
            if (gm < M) av = *(const u16x8*)(A + (size_t)gm * lda + k0 + kb);
            *(u16x8*)(As + rr * 40 + kb) = av;
            int gn = bn * 128 + rr;
            *(u16x8*)(Bs + rr * 40 + kb) = *(const u16x8*)(B + (size_t)gn * ldb + k0 + kb);
        }
        __syncthreads();
        bf16x8 af[4], bfr[4];
#pragma unroll
        for (int i = 0; i < 4; i++) af[i] = *(const bf16x8*)(As + (wm + i * 16 + lr) * 40 + quad * 8);
#pragma unroll
        for (int j = 0; j < 4; j++) bfr[j] = *(const bf16x8*)(Bs + (wn + j * 16 + lr) * 40 + quad * 8);
#pragma unroll
        for (int i = 0; i < 4; i++)
#pragma unroll
            for (int j = 0; j < 4; j++)
                acc[i][j] = __builtin_amdgcn_mfma_f32_16x16x32_bf16(af[i], bfr[j], acc[i][j], 0, 0, 0);
        __syncthreads();
    }

#pragma unroll
    for (int i = 0; i < 4; i++) {
        int gm0 = bm * 128 + wm + i * 16 + quad * 4;
#pragma unroll
        for (int j = 0; j < 4; j++) {
            int gn = bn * 128 + wn + j * 16 + lr;
#pragma unroll
            for (int reg = 0; reg < 4; reg++) {
                int gm = gm0 + reg;
                if (gm >= M) continue;
                float v = acc[i][j][reg];
                size_t o = (size_t)gm * N + gn;
                if constexpr (MODE == 0) ((float*)C)[o] = v;
                else if constexpr (MODE == 1) ((float*)C)[o] = v + bias[gn];
                else if constexpr (MODE == 2) ((u16*)C)[o] = f2bf(v + bias[gn]);
                else if constexpr (MODE == 3) ((float*)C)[o] = v + prevf[o];
                else if constexpr (MODE == 4)
                    ((u16*)C)[o] = f2bf(tanhf(v + prevf[o] + addb[(size_t)(gm & 63) * N + gn]));
                else if constexpr (MODE == 5) ((u16*)C)[o] = f2bf(sigf(v + bias[gn]));
            }
        }
    }
}

// ---------------- persistent attention-GRU episode kernel ----------------
// 64 blocks; block owns d-slice [ds, ds+16). LDS-resident Whh slice: 48 rows
// (3 gates x 16 d) x 1024, stride 1032 (bank start 4*row%32 -> 2-way = free).
// Per step: A (h) fragments direct from global (dbuf 8-iter chunks), 3 MFMA
// per k-iter against LDS B, gate math on register fp32 h, grid barrier.
// Step t reads hA if t even else hB, writes the other; 128 steps -> final in hA.
__global__ __launch_bounds__(256) void gru_persist(
    const u16* __restrict__ Whh, const float* __restrict__ bhh,
    const u16* __restrict__ GIb, const u16* __restrict__ G,
    u16* __restrict__ hA, u16* __restrict__ hB,
    unsigned* __restrict__ bar) {
    extern __shared__ u16 Ws[];  // 48 * 1032
    const int tid = threadIdx.x;
    const int ds = blockIdx.x * 16;
    const int w = tid >> 6, lane = tid & 63, lr = lane & 15, quad = lane >> 4;

    // stage Whh slice once: local row r -> gate g=r>>4, d = ds + (r&15)
    for (int idx = tid; idx < 48 * 128; idx += 256) {
        int r = idx >> 7, col8 = (idx & 127) * 8;
        int g = r >> 4, dl = r & 15;
        *(u16x8*)(Ws + r * 1032 + col8) =
            *(const u16x8*)(Whh + (size_t)(g * 1024 + ds + dl) * 1024 + col8);
    }
    __syncthreads();

    // lane state: (b = w*16 + quad*4 + reg, d = ds + lr)
    const int b0 = w * 16 + quad * 4;
    const int d = ds + lr;
    const float bhr = bhh[d], bhz = bhh[1024 + d], bhn = bhh[2048 + d];
    f32x4 h = {0.f, 0.f, 0.f, 0.f};

    const u16* wsr = Ws + lr * 1032 + quad * 8;

    for (int t = 0; t < 128; t++) {
        const u16* hin = (t & 1) ? hB : hA;
        u16* hout = (t & 1) ? hA : hB;

        // epilogue operands for this step (issue early, consumed after K-loop)
        const u16* GIt = GIb + (size_t)t * 64 * 3072;
        const u16* Gt = G + (size_t)t * 64 * 1024;
        u16 gir[4], giz[4], gin[4], gg[4];
#pragma unroll
        for (int reg = 0; reg < 4; reg++) {
            int b = b0 + reg;
            gir[reg] = GIt[b * 3072 + d];
            giz[reg] = GIt[b * 3072 + 1024 + d];
            gin[reg] = GIt[b * 3072 + 2048 + d];
            gg[reg] = Gt[b * 1024 + d];
        }

        // K-loop: 32 iters of K=32; A double-buffered in 8-iter chunks
        f32x4 ar = {0.f, 0.f, 0.f, 0.f}, az = ar, an = ar;
        const u16* arow = hin + (w * 16 + lr) * 1024 + quad * 8;
        u16x8 abuf[2][8];
#pragma unroll
        for (int j = 0; j < 8; j++) abuf[0][j] = *(const u16x8*)(arow + j * 32);
#pragma unroll
        for (int ch = 0; ch < 4; ch++) {
            if (ch < 3) {
#pragma unroll
                for (int j = 0; j < 8; j++)
                    abuf[(ch + 1) & 1][j] = *(const u16x8*)(arow + (ch + 1) * 256 + j * 32);
            }
#pragma unroll
            for (int j = 0; j < 8; j++) {
                int k0 = ch * 256 + j * 32;
                bf16x8 av = *(bf16x8*)&abuf[ch & 1][j];
                bf16x8 br = *(const bf16x8*)(wsr + k0);
                bf16x8 bz = *(const bf16x8*)(wsr + 16 * 1032 + k0);
                bf16x8 bn = *(const bf16x8*)(wsr + 32 * 1032 + k0);
                ar = __builtin_amdgcn_mfma_f32_16x16x32_bf16(av, br, ar, 0, 0, 0);
                az = __builtin_amdgcn_mfma_f32_16x16x32_bf16(av, bz, az, 0, 0, 0);
                an = __builtin_amdgcn_mfma_f32_16x16x32_bf16(av, bn, an, 0, 0, 0);
            }
        }

        // gate math on register h state; write bf16 h for next step's A-loads
#pragma unroll
        for (int reg = 0; reg < 4; reg++) {
            float r = sigf(bf2f(gir[reg]) + ar[reg] + bhr);
            float z = sigf(bf2f(giz[reg]) + az[reg] + bhz);
            float n = tanhf(bf2f(gin[reg]) + r * (an[reg] + bhn));
            float hatt = (1.f - z) * n + z * h[reg];
            float g = bf2f(gg[reg]);
            h[reg] = g * hatt + (1.f - g) * h[reg];
            hout[(b0 + reg) * 1024 + d] = f2bf(h[reg]);
        }

        // grid barrier: all writes visible device-wide, then arrive+wait
        __threadfence();
        __syncthreads();
        if (tid == 0) {
            __hip_atomic_fetch_add(bar, 1u, __ATOMIC_RELEASE, __HIP_MEMORY_SCOPE_AGENT);
            unsigned target = 64u * (unsigned)(t + 1);
            while (__hip_atomic_load(bar, __ATOMIC_ACQUIRE, __HIP_MEMORY_SCOPE_AGENT) < target)
                __builtin_amdgcn_s_sleep(2);
        }
        __syncthreads();
    }
}

// ---------------- mem GRU cell: m' = GRUCell(e, m) ----------------
__global__ __launch_bounds__(256) void gru_mem(
    const u16* __restrict__ ebf, const u16* __restrict__ mbf,
    const float* __restrict__ mold,
    const u16* __restrict__ Wih, const u16* __restrict__ Whh,
    const float* __restrict__ bih, const float* __restrict__ bhh,
    float* __restrict__ mout, u16* __restrict__ mbf_out) {
    __shared__ u16 es[64 * 40];
    __shared__ u16 ms[64 * 40];
    __shared__ u16 Wi[192 * 40];
    __shared__ u16 Wh[192 * 40];
    const int t = threadIdx.x;
    const int ds = blockIdx.x * 64;
    const int w = t >> 6, lane = t & 63, lr = lane & 15, quad = lane >> 4;
    const int r0 = t >> 2, kb = (t & 3) * 8;

    f32x4 zero4 = {0.f, 0.f, 0.f, 0.f};
    f32x4 ai[4][3], ah[4][3];
#pragma unroll
    for (int i = 0; i < 4; i++)
#pragma unroll
        for (int g = 0; g < 3; g++) { ai[i][g] = zero4; ah[i][g] = zero4; }

    for (int k0 = 0; k0 < 1024; k0 += 32) {
        *(u16x8*)(es + r0 * 40 + kb) = *(const u16x8*)(ebf + r0 * 1024 + k0 + kb);
        *(u16x8*)(ms + r0 * 40 + kb) = *(const u16x8*)(mbf + r0 * 1024 + k0 + kb);
#pragma unroll
        for (int ln = r0; ln < 192; ln += 64) {
            int g = ln >> 6, dl = ln & 63;
            size_t ro = (size_t)(g * 1024 + ds + dl) * 1024 + k0 + kb;
            *(u16x8*)(Wi + ln * 40 + kb) = *(const u16x8*)(Wih + ro);
            *(u16x8*)(Wh + ln * 40 + kb) = *(const u16x8*)(Whh + ro);
        }
        __syncthreads();
        bf16x8 ae[4], am[4], bi[3], bh[3];
#pragma unroll
        for (int i = 0; i < 4; i++) {
            ae[i] = *(const bf16x8*)(es + (i * 16 + lr) * 40 + quad * 8);
            am[i] = *(const bf16x8*)(ms + (i * 16 + lr) * 40 + quad * 8);
        }
#pragma unroll
        for (int g = 0; g < 3; g++) {
            bi[g] = *(const bf16x8*)(Wi + (g * 64 + w * 16 + lr) * 40 + quad * 8);
            bh[g] = *(const bf16x8*)(Wh + (g * 64 + w * 16 + lr) * 40 + quad * 8);
        }
#pragma unroll
        for (int i = 0; i < 4; i++)
#pragma unroll
            for (int g = 0; g < 3; g++) {
                ai[i][g] = __builtin_amdgcn_mfma_f32_16x16x32_bf16(ae[i], bi[g], ai[i][g], 0, 0, 0);
                ah[i][g] = __builtin_amdgcn_mfma_f32_16x16x32_bf16(am[i], bh[g], ah[i][g], 0, 0, 0);
            }
        __syncthreads();
    }

    const int d = ds + w * 16 + lr;
    const float bir = bih[d], biz = bih[1024 + d], bin = bih[2048 + d];
    const float bhr = bhh[d], bhz = bhh[1024 + d], bhn = bhh[2048 + d];
#pragma unroll
    for (int i = 0; i < 4; i++) {
#pragma unroll
        for (int reg = 0; reg < 4; reg++) {
            int b = i * 16 + quad * 4 + reg;
            float r = sigf(ai[i][0][reg] + bir + ah[i][0][reg] + bhr);
            float z = sigf(ai[i][1][reg] + biz + ah[i][1][reg] + bhz);
            float n = tanhf(ai[i][2][reg] + bin + r * (ah[i][2][reg] + bhn));
            float mo = mold[b * 1024 + d];
            float mn = (1.f - z) * n + z * mo;
            mout[b * 1024 + d] = mn;
            mbf_out[b * 1024 + d] = f2bf(mn);
        }
    }
}

// ---------------------------------------------------------------------------
extern "C" void kernel_launch(void* const* d_in, const int* in_sizes, int n_in,
                              void* d_out, int out_size, void* d_ws, size_t ws_size,
                              hipStream_t stream) {
    const float* c    = (const float*)d_in[0];
    const float* q    = (const float*)d_in[1];
    const float* Wb   = (const float*)d_in[2];
    const float* W1   = (const float*)d_in[3];
    const float* W1b  = (const float*)d_in[4];
    const float* W2   = (const float*)d_in[5];
    const float* W2b  = (const float*)d_in[6];
    const float* mWih = (const float*)d_in[7];
    const float* mWhh = (const float*)d_in[8];
    const float* mbih = (const float*)d_in[9];
    const float* mbhh = (const float*)d_in[10];
    const float* aWih = (const float*)d_in[11];
    const float* aWhh = (const float*)d_in[12];
    const float* abih = (const float*)d_in[13];
    const float* abhh = (const float*)d_in[14];

    char* p = (char*)d_ws;
    auto nb = [&](size_t bytes) -> char* {
        char* r = p; p += (bytes + 255) & ~(size_t)255; return r;
    };
    u16* W1p     = (u16*)nb(1024ull * 9216 * 2);   // 18 MiB
    u16* Wb_bf   = (u16*)nb(1024ull * 1024 * 2);
    u16* W2_bf   = (u16*)nb(1024ull * 1024 * 2);
    u16* aWih_bf = (u16*)nb(3072ull * 1024 * 2);
    u16* aWhh_bf = (u16*)nb(3072ull * 1024 * 2);
    u16* mWih_bf = (u16*)nb(3072ull * 1024 * 2);
    u16* mWhh_bf = (u16*)nb(3072ull * 1024 * 2);
    u16* qbf     = (u16*)nb(64 * 1024 * 2);
    u16* m1bf    = (u16*)nb(64 * 1024 * 2);
    u16* m2bf    = (u16*)nb(64 * 1024 * 2);
    u16* hA      = (u16*)nb(64 * 1024 * 2);
    u16* hB      = (u16*)nb(64 * 1024 * 2);
    u16* Zq      = (u16*)nb(8192ull * 4096 * 2);   // 64 MiB (Zm aliases)
    u16* GIb     = (u16*)nb(8192ull * 3072 * 2);   // 48 MiB
    u16* G1      = (u16*)nb(8192ull * 1024 * 2);   // 16 MiB
    u16* G       = (u16*)nb(8192ull * 1024 * 2);   // 16 MiB
    float* P0    = (float*)nb(8192ull * 1024 * 4); // 32 MiB
    float* Wbq   = (float*)nb(64 * 1024 * 4);
    float* Wbm   = (float*)nb(64 * 1024 * 4);
    float* addq  = (float*)nb(64 * 1024 * 4);
    float* addt  = (float*)nb(64 * 1024 * 4);
    float* m1    = (float*)nb(64 * 1024 * 4);
    unsigned* bar = (unsigned*)nb(256);
    u16* Zm      = Zq;  // alias: Zq dead once episode-0 G1 GEMM completes

    size_t needed = (size_t)(p - (char*)d_ws);
    if (needed > ws_size) {
        fill_sentinel<<<256, 256, 0, stream>>>((float*)d_out, out_size, 12345.0f);
        return;
    }

    // allow >64 KiB dynamic LDS for the persistent kernel (idempotent)
    static bool attr_set = false;
    const int ws_lds = 48 * 1032 * 2;  // 99072 B
    if (!attr_set) {
        (void)hipFuncSetAttribute((const void*)gru_persist,
                                  hipFuncAttributeMaxDynamicSharedMemorySize, ws_lds);
        attr_set = true;
    }

    // weight converts
    conv_bf<<<256, 256, 0, stream>>>(q, qbf, 64 * 1024);
    conv_bf<<<2048, 256, 0, stream>>>(Wb, Wb_bf, 1024 * 1024);
    conv_bf<<<2048, 256, 0, stream>>>(W2, W2_bf, 1024 * 1024);
    conv_bf<<<4096, 256, 0, stream>>>(aWih, aWih_bf, 3072 * 1024);
    conv_bf<<<4096, 256, 0, stream>>>(aWhh, aWhh_bf, 3072 * 1024);
    conv_bf<<<4096, 256, 0, stream>>>(mWih, mWih_bf, 3072 * 1024);
    conv_bf<<<4096, 256, 0, stream>>>(mWhh, mWhh_bf, 3072 * 1024);
    repack_w1<<<8192, 256, 0, stream>>>(W1, W1p);

    // episode-invariant precompute
    gemm_bt<0><<<dim3(8, 1), 256, 0, stream>>>(qbf, 1024, Wb_bf, 1024, Wbq, 64, 1024, 1024,
                                               nullptr, nullptr, nullptr);
    gemm_bt<1><<<dim3(8, 1), 256, 0, stream>>>(qbf, 1024, W1p + 8192, 9216, addq, 64, 1024, 1024,
                                               W1b, nullptr, nullptr);
    build_zq<<<16384, 256, 0, stream>>>(c, q, Wbq, Zq);
    gemm_bt<0><<<dim3(8, 64), 256, 0, stream>>>(Zq, 4096, W1p, 9216, P0, 8192, 1024, 4096,
                                                nullptr, nullptr, nullptr);
    gemm_bt<2><<<dim3(24, 64), 256, 0, stream>>>(Zq, 4096, aWih_bf, 1024, GIb, 8192, 3072, 1024,
                                                 abih, nullptr, nullptr);

    for (int ep = 0; ep < 2; ep++) {
        const u16* mbf_cur = ep ? m1bf : qbf;
        const float* mold  = ep ? (const float*)m1 : q;
        // addterm = m@W1_blk1 + (q@W1_blk2 + b1)
        gemm_bt<3><<<dim3(8, 1), 256, 0, stream>>>(mbf_cur, 1024, W1p + 7168, 9216, addt,
                                                   64, 1024, 1024, nullptr, addq, nullptr);
        const u16* AG1; int ldaG1;
        if (ep) {
            gemm_bt<0><<<dim3(8, 1), 256, 0, stream>>>(m1bf, 1024, Wb_bf, 1024, Wbm,
                                                       64, 1024, 1024, nullptr, nullptr, nullptr);
            build_zm<<<16384, 256, 0, stream>>>(c, m1, Wbm, Zm);
            AG1 = Zm; ldaG1 = 3072;
        } else {
            AG1 = Zq + 1024; ldaG1 = 4096;  // m==q: reuse invariant features
        }
        gemm_bt<4><<<dim3(8, 64), 256, 0, stream>>>(AG1, ldaG1, W1p + 4096, 9216, G1,
                                                    8192, 1024, 3072, nullptr, P0, addt);
        gemm_bt<5><<<dim3(8, 64), 256, 0, stream>>>(G1, 1024, W2_bf, 1024, G,
                                                    8192, 1024, 1024, W2b, nullptr, nullptr);

        // persistent 128-step episode: zero h + barrier, then one launch
        zero_state<<<64, 256, 0, stream>>>(hA, bar, 64 * 1024);
        gru_persist<<<64, 256, ws_lds, stream>>>(aWhh_bf, abhh, GIb, G, hA, hB, bar);

        // 128 steps (even) -> final h in hA
        float* mo = ep ? (float*)d_out : m1;
        u16* mob = ep ? m2bf : m1bf;
        gru_mem<<<16, 256, 0, stream>>>(hA, mbf_cur, mold, mWih_bf, mWhh_bf,
                                        mbih, mbhh, mo, mob);
    }
}

// Round 4
// 4381.343 us; speedup vs baseline: 2.1600x; 1.1000x over previous
//
#include <hip/hip_runtime.h>

// ---------------------------------------------------------------------------
// EpisodicMemoryModule: T=128, B=64, D=1024, 2 episodes.
//   - Feature GEMM z@W1^T split into 9 K-blocks; invariants hoisted (P0, K=4096),
//     per-episode blocks (K=3072), rank-64 terms folded into epilogue.
//   - Episode 0 reuses invariant features (m == q).
//   - att-GRU input gi = c@Wih^T batched over all t (GI, M=8192).
//   - Serial part: persistent kernel, 64 blocks x 16-d slice, Whh in LDS.
//     h exchanged via SYSTEM-scope relaxed atomics (sc0 sc1, cache-bypass,
//     coherent at LLC) -> no per-step L2 writeback/invalidate storms.
//     Grid barrier: per-block padded arrival slots + block-0 gather + go flag
//     (no shared-line RMW contention).
// ---------------------------------------------------------------------------

typedef unsigned short u16;
typedef unsigned long long u64;
typedef __attribute__((ext_vector_type(8))) short bf16x8;
typedef __attribute__((ext_vector_type(8))) unsigned short u16x8;
typedef __attribute__((ext_vector_type(4))) float f32x4;

__device__ inline float bf2f(u16 u) {
    union { unsigned u; float f; } v; v.u = ((unsigned)u) << 16; return v.f;
}
__device__ inline u16 f2bf(float f) {
    union { float f; unsigned u; } v; v.f = f;
    unsigned r = v.u + 0x7fff + ((v.u >> 16) & 1);
    return (u16)(r >> 16);
}
__device__ inline float sigf(float x) { return 1.f / (1.f + expf(-x)); }

__device__ inline u64 cload64(const u16* p) {
    return __hip_atomic_load((const u64*)p, __ATOMIC_RELAXED, __HIP_MEMORY_SCOPE_SYSTEM);
}
__device__ inline void cstore64(u16* p, u64 v) {
    __hip_atomic_store((u64*)p, v, __ATOMIC_RELAXED, __HIP_MEMORY_SCOPE_SYSTEM);
}

__global__ void fill_sentinel(float* __restrict__ d, int n, float v) {
    for (int i = blockIdx.x * 256 + threadIdx.x; i < n; i += gridDim.x * 256) d[i] = v;
}

// zero h state (via coherent stores so no L2 copy ever exists) + barrier slots
__global__ void zero_state(u16* __restrict__ hb, unsigned* __restrict__ slots, int n) {
    int i = blockIdx.x * 256 + threadIdx.x;
    for (int j = i; j < n / 4; j += gridDim.x * 256)
        __hip_atomic_store((u64*)hb + j, 0ull, __ATOMIC_RELAXED, __HIP_MEMORY_SCOPE_SYSTEM);
    if (i < 1088)
        __hip_atomic_store(slots + i, 0u, __ATOMIC_RELAXED, __HIP_MEMORY_SCOPE_SYSTEM);
}

// ---------------- elementwise converts ----------------
__global__ void conv_bf(const float* __restrict__ s, u16* __restrict__ d, int n) {
    for (int i = blockIdx.x * 256 + threadIdx.x; i < n; i += gridDim.x * 256)
        d[i] = f2bf(s[i]);
}

// Repack W1 [1024][9216] -> bf16 with K-block order {0,3,5,7, 4,6,8, 1, 2}
__global__ void repack_w1(const float* __restrict__ W1, u16* __restrict__ out) {
    const int jmap[9] = {0, 3, 5, 7, 4, 6, 8, 1, 2};
    const int total = 1024 * 9216;
    for (int i = blockIdx.x * 256 + threadIdx.x; i < total; i += gridDim.x * 256) {
        int n = i / 9216;
        int rest = i - n * 9216;
        int v = rest >> 10, k = rest & 1023;
        out[(size_t)n * 9216 + rest] = f2bf(W1[(size_t)n * 9216 + jmap[v] * 1024 + k]);
    }
}

// Zq[(t*64+b)][4096] = bf16{ c, c*q, |c-q|, c*Wbq }
__global__ void build_zq(const float* __restrict__ c, const float* __restrict__ q,
                         const float* __restrict__ wbq, u16* __restrict__ Zq) {
    const int total = 8192 * 1024;
    for (int i = blockIdx.x * 256 + threadIdx.x; i < total; i += gridDim.x * 256) {
        int row = i >> 10, k = i & 1023, b = row & 63;
        float cv = c[i];
        float qv = q[b * 1024 + k];
        float wv = wbq[b * 1024 + k];
        size_t ro = (size_t)row * 4096;
        Zq[ro + k]        = f2bf(cv);
        Zq[ro + 1024 + k] = f2bf(cv * qv);
        Zq[ro + 2048 + k] = f2bf(fabsf(cv - qv));
        Zq[ro + 3072 + k] = f2bf(cv * wv);
    }
}

// Zm[(t*64+b)][3072] = bf16{ c*m, |c-m|, c*Wbm }
__global__ void build_zm(const float* __restrict__ c, const float* __restrict__ m,
                         const float* __restrict__ wbm, u16* __restrict__ Zm) {
    const int total = 8192 * 1024;
    for (int i = blockIdx.x * 256 + threadIdx.x; i < total; i += gridDim.x * 256) {
        int row = i >> 10, k = i & 1023, b = row & 63;
        float cv = c[i];
        float mv = m[b * 1024 + k];
        float wv = wbm[b * 1024 + k];
        size_t ro = (size_t)row * 3072;
        Zm[ro + k]        = f2bf(cv * mv);
        Zm[ro + 1024 + k] = f2bf(fabsf(cv - mv));
        Zm[ro + 2048 + k] = f2bf(cv * wv);
    }
}

// ---------------- generic C = A @ B^T GEMM (bf16 in, fp32 acc) ----------------
// MODE 0: fp32 out           1: fp32 out + bias[n]       2: bf16 out + bias[n]
//      3: fp32 out + prevf[m][n]
//      4: bf16 out = tanh(acc + prevf[m][n] + addb[m&63][n])
//      5: bf16 out = sigmoid(acc + bias[n])
template <int MODE>
__global__ __launch_bounds__(256) void gemm_bt(
    const u16* __restrict__ A, int lda,
    const u16* __restrict__ B, int ldb,
    void* __restrict__ C, int M, int N, int K,
    const float* __restrict__ bias,
    const float* __restrict__ prevf,
    const float* __restrict__ addb) {
    __shared__ u16 As[128 * 40];
    __shared__ u16 Bs[128 * 40];
    const int t = threadIdx.x;
    const int bn = blockIdx.x, bm = blockIdx.y;
    const int w = t >> 6, lane = t & 63, lr = lane & 15, quad = lane >> 4;
    const int wm = (w >> 1) * 64, wn = (w & 1) * 64;
    const int r0 = t >> 2, kb = (t & 3) * 8;

    f32x4 zero4 = {0.f, 0.f, 0.f, 0.f};
    f32x4 acc[4][4];
#pragma unroll
    for (int i = 0; i < 4; i++)
#pragma unroll
        for (int j = 0; j < 4; j++) acc[i][j] = zero4;

    const u16x8 zz = {0, 0, 0, 0, 0, 0, 0, 0};

    for (int k0 = 0; k0 < K; k0 += 32) {
#pragma unroll
        for (int rr = r0; rr < 128; rr += 64) {
            int gm = bm * 128 + rr;
            u16x8 av = zz;
            if (gm < M) av = *(const u16x8*)(A + (size_t)gm * lda + k0 + kb);
            *(u16x8*)(As + rr * 40 + kb) = av;
            int gn = bn * 128 + rr;
            *(u16x8*)(Bs + rr * 40 + kb) = *(const u16x8*)(B + (size_t)gn * ldb + k0 + kb);
        }
        __syncthreads();
        bf16x8 af[4], bfr[4];
#pragma unroll
        for (int i = 0; i < 4; i++) af[i] = *(const bf16x8*)(As + (wm + i * 16 + lr) * 40 + quad * 8);
#pragma unroll
        for (int j = 0; j < 4; j++) bfr[j] = *(const bf16x8*)(Bs + (wn + j * 16 + lr) * 40 + quad * 8);
#pragma unroll
        for (int i = 0; i < 4; i++)
#pragma unroll
            for (int j = 0; j < 4; j++)
                acc[i][j] = __builtin_amdgcn_mfma_f32_16x16x32_bf16(af[i], bfr[j], acc[i][j], 0, 0, 0);
        __syncthreads();
    }

#pragma unroll
    for (int i = 0; i < 4; i++) {
        int gm0 = bm * 128 + wm + i * 16 + quad * 4;
#pragma unroll
        for (int j = 0; j < 4; j++) {
            int gn = bn * 128 + wn + j * 16 + lr;
#pragma unroll
            for (int reg = 0; reg < 4; reg++) {
                int gm = gm0 + reg;
                if (gm >= M) continue;
                float v = acc[i][j][reg];
                size_t o = (size_t)gm * N + gn;
                if constexpr (MODE == 0) ((float*)C)[o] = v;
                else if constexpr (MODE == 1) ((float*)C)[o] = v + bias[gn];
                else if constexpr (MODE == 2) ((u16*)C)[o] = f2bf(v + bias[gn]);
                else if constexpr (MODE == 3) ((float*)C)[o] = v + prevf[o];
                else if constexpr (MODE == 4)
                    ((u16*)C)[o] = f2bf(tanhf(v + prevf[o] + addb[(size_t)(gm & 63) * N + gn]));
                else if constexpr (MODE == 5) ((u16*)C)[o] = f2bf(sigf(v + bias[gn]));
            }
        }
    }
}

// ---------------- persistent attention-GRU episode kernel ----------------
// 64 blocks; block owns d-slice [ds, ds+16). LDS: Whh A-slice, 48 rows
// (3 gates x 16 d) x 1024, stride 1032.
// MFMA roles: A = Whh rows (d), B = h rows (b)  ->  C[d-local][b-tile];
// lane owns (b = w*16 + (lane&15), d = ds + quad*4 + reg): h store is one
// 64-bit coherent store, GI/G loads are 64-bit loads.
// h exchange: system-scope relaxed atomics only (no L2 copies anywhere).
// Barrier: padded per-block slots (release store) -> block0 wave0 gather ->
// go flag (release store); all blocks acquire-spin on go. No RMW contention.
__global__ __launch_bounds__(256, 1) void gru_persist(
    const u16* __restrict__ Whh, const float* __restrict__ bhh,
    const u16* __restrict__ GIb, const u16* __restrict__ G,
    u16* __restrict__ hA, u16* __restrict__ hB,
    unsigned* __restrict__ slots) {
    extern __shared__ u16 Ws[];  // 48 * 1032
    unsigned* goflag = slots + 1024;  // slots: 64 x 16 u32 padded; go at +1024
    const int tid = threadIdx.x;
    const int bid = blockIdx.x;
    const int ds = bid * 16;
    const int w = tid >> 6, lane = tid & 63, lr = lane & 15, quad = lane >> 4;

    // stage Whh A-slice once: row r = g*16 + dl -> Whh[g*1024 + ds + dl][:]
    for (int idx = tid; idx < 48 * 128; idx += 256) {
        int r = idx >> 7, col8 = (idx & 127) * 8;
        int g = r >> 4, dl = r & 15;
        *(u16x8*)(Ws + r * 1032 + col8) =
            *(const u16x8*)(Whh + (size_t)(g * 1024 + ds + dl) * 1024 + col8);
    }
    __syncthreads();

    const int b = w * 16 + lr;         // lane's batch row
    const int d0 = ds + quad * 4;      // lane's first d (4 contiguous)
    f32x4 bhr4 = *(const f32x4*)(bhh + d0);
    f32x4 bhz4 = *(const f32x4*)(bhh + 1024 + d0);
    f32x4 bhn4 = *(const f32x4*)(bhh + 2048 + d0);
    f32x4 h = {0.f, 0.f, 0.f, 0.f};

    const u16* wsA = Ws + lr * 1032 + quad * 8;  // A-frag: row=lr (d), k=quad*8+j

    for (int t = 0; t < 128; t++) {
        const u16* hin = (t & 1) ? hB : hA;
        u16* hout = (t & 1) ? hA : hB;

        // step operands (independent of h; overlap with h loads)
        const u16* GIt = GIb + (size_t)t * 196608;
        const u16* Gt = G + (size_t)t * 65536;
        u64 pgir = *(const u64*)(GIt + b * 3072 + d0);
        u64 pgiz = *(const u64*)(GIt + b * 3072 + 1024 + d0);
        u64 pgin = *(const u64*)(GIt + b * 3072 + 2048 + d0);
        u64 pgg  = *(const u64*)(Gt + b * 1024 + d0);

        // preload ALL B-fragments of h (coherent, bypass L1/L2): 64 x 8B
        const u16* hrow = hin + b * 1024 + quad * 8;
        u64 hq0[32], hq1[32];
#pragma unroll
        for (int ki = 0; ki < 32; ki++) {
            hq0[ki] = cload64(hrow + ki * 32);
            hq1[ki] = cload64(hrow + ki * 32 + 4);
        }

        f32x4 accr = {0.f, 0.f, 0.f, 0.f}, accz = accr, accn = accr;
#pragma unroll
        for (int ki = 0; ki < 32; ki++) {
            union { u64 q[2]; bf16x8 v; } u;
            u.q[0] = hq0[ki]; u.q[1] = hq1[ki];
            int k0 = ki * 32;
            bf16x8 a_r = *(const bf16x8*)(wsA + k0);
            bf16x8 a_z = *(const bf16x8*)(wsA + 16 * 1032 + k0);
            bf16x8 a_n = *(const bf16x8*)(wsA + 32 * 1032 + k0);
            accr = __builtin_amdgcn_mfma_f32_16x16x32_bf16(a_r, u.v, accr, 0, 0, 0);
            accz = __builtin_amdgcn_mfma_f32_16x16x32_bf16(a_z, u.v, accz, 0, 0, 0);
            accn = __builtin_amdgcn_mfma_f32_16x16x32_bf16(a_n, u.v, accn, 0, 0, 0);
        }

        // gate math on register h state; one 64-bit coherent store
        u64 outv = 0;
#pragma unroll
        for (int reg = 0; reg < 4; reg++) {
            float r = sigf(bf2f((u16)(pgir >> (16 * reg))) + accr[reg] + bhr4[reg]);
            float z = sigf(bf2f((u16)(pgiz >> (16 * reg))) + accz[reg] + bhz4[reg]);
            float n = tanhf(bf2f((u16)(pgin >> (16 * reg))) + r * (accn[reg] + bhn4[reg]));
            float hatt = (1.f - z) * n + z * h[reg];
            float g = bf2f((u16)(pgg >> (16 * reg)));
            h[reg] = g * hatt + (1.f - g) * h[reg];
            outv |= (u64)f2bf(h[reg]) << (16 * reg);
        }
        cstore64(hout + b * 1024 + d0, outv);

        if (t == 127) break;  // no barrier after the last step

        // ---- two-level grid barrier, epoch = t+1 ----
        unsigned epoch = (unsigned)(t + 1);
        __syncthreads();  // drains this block's h stores (waitcnt before s_barrier)
        if (tid == 0)
            __hip_atomic_store(slots + bid * 16, epoch, __ATOMIC_RELEASE,
                               __HIP_MEMORY_SCOPE_SYSTEM);
        if (bid == 0) {
            if (tid < 64) {
                while (__hip_atomic_load(slots + tid * 16, __ATOMIC_ACQUIRE,
                                         __HIP_MEMORY_SCOPE_SYSTEM) < epoch)
                    __builtin_amdgcn_s_sleep(1);
            }
            __syncthreads();
            if (tid == 0)
                __hip_atomic_store(goflag, epoch, __ATOMIC_RELEASE,
                                   __HIP_MEMORY_SCOPE_SYSTEM);
        }
        if (tid == 0) {
            while (__hip_atomic_load(goflag, __ATOMIC_ACQUIRE,
                                     __HIP_MEMORY_SCOPE_SYSTEM) < epoch)
                __builtin_amdgcn_s_sleep(1);
        }
        __syncthreads();
    }
}

// ---------------- mem GRU cell: m' = GRUCell(e, m) ----------------
__global__ __launch_bounds__(256) void gru_mem(
    const u16* __restrict__ ebf, const u16* __restrict__ mbf,
    const float* __restrict__ mold,
    const u16* __restrict__ Wih, const u16* __restrict__ Whh,
    const float* __restrict__ bih, const float* __restrict__ bhh,
    float* __restrict__ mout, u16* __restrict__ mbf_out) {
    __shared__ u16 es[64 * 40];
    __shared__ u16 ms[64 * 40];
    __shared__ u16 Wi[192 * 40];
    __shared__ u16 Wh[192 * 40];
    const int t = threadIdx.x;
    const int ds = blockIdx.x * 64;
    const int w = t >> 6, lane = t & 63, lr = lane & 15, quad = lane >> 4;
    const int r0 = t >> 2, kb = (t & 3) * 8;

    f32x4 zero4 = {0.f, 0.f, 0.f, 0.f};
    f32x4 ai[4][3], ah[4][3];
#pragma unroll
    for (int i = 0; i < 4; i++)
#pragma unroll
        for (int g = 0; g < 3; g++) { ai[i][g] = zero4; ah[i][g] = zero4; }

    for (int k0 = 0; k0 < 1024; k0 += 32) {
        // e (final h) was written via coherent stores -> read coherently
        union { u64 q[2]; u16x8 v; } eu;
        eu.q[0] = cload64(ebf + r0 * 1024 + k0 + kb);
        eu.q[1] = cload64(ebf + r0 * 1024 + k0 + kb + 4);
        *(u16x8*)(es + r0 * 40 + kb) = eu.v;
        *(u16x8*)(ms + r0 * 40 + kb) = *(const u16x8*)(mbf + r0 * 1024 + k0 + kb);
#pragma unroll
        for (int ln = r0; ln < 192; ln += 64) {
            int g = ln >> 6, dl = ln & 63;
            size_t ro = (size_t)(g * 1024 + ds + dl) * 1024 + k0 + kb;
            *(u16x8*)(Wi + ln * 40 + kb) = *(const u16x8*)(Wih + ro);
            *(u16x8*)(Wh + ln * 40 + kb) = *(const u16x8*)(Whh + ro);
        }
        __syncthreads();
        bf16x8 ae[4], am[4], bi[3], bh[3];
#pragma unroll
        for (int i = 0; i < 4; i++) {
            ae[i] = *(const bf16x8*)(es + (i * 16 + lr) * 40 + quad * 8);
            am[i] = *(const bf16x8*)(ms + (i * 16 + lr) * 40 + quad * 8);
        }
#pragma unroll
        for (int g = 0; g < 3; g++) {
            bi[g] = *(const bf16x8*)(Wi + (g * 64 + w * 16 + lr) * 40 + quad * 8);
            bh[g] = *(const bf16x8*)(Wh + (g * 64 + w * 16 + lr) * 40 + quad * 8);
        }
#pragma unroll
        for (int i = 0; i < 4; i++)
#pragma unroll
            for (int g = 0; g < 3; g++) {
                ai[i][g] = __builtin_amdgcn_mfma_f32_16x16x32_bf16(ae[i], bi[g], ai[i][g], 0, 0, 0);
                ah[i][g] = __builtin_amdgcn_mfma_f32_16x16x32_bf16(am[i], bh[g], ah[i][g], 0, 0, 0);
            }
        __syncthreads();
    }

    const int d = ds + w * 16 + lr;
    const float bir = bih[d], biz = bih[1024 + d], bin = bih[2048 + d];
    const float bhr = bhh[d], bhz = bhh[1024 + d], bhn = bhh[2048 + d];
#pragma unroll
    for (int i = 0; i < 4; i++) {
#pragma unroll
        for (int reg = 0; reg < 4; reg++) {
            int b = i * 16 + quad * 4 + reg;
            float r = sigf(ai[i][0][reg] + bir + ah[i][0][reg] + bhr);
            float z = sigf(ai[i][1][reg] + biz + ah[i][1][reg] + bhz);
            float n = tanhf(ai[i][2][reg] + bin + r * (ah[i][2][reg] + bhn));
            float mo = mold[b * 1024 + d];
            float mn = (1.f - z) * n + z * mo;
            mout[b * 1024 + d] = mn;
            mbf_out[b * 1024 + d] = f2bf(mn);
        }
    }
}

// ---------------------------------------------------------------------------
extern "C" void kernel_launch(void* const* d_in, const int* in_sizes, int n_in,
                              void* d_out, int out_size, void* d_ws, size_t ws_size,
                              hipStream_t stream) {
    const float* c    = (const float*)d_in[0];
    const float* q    = (const float*)d_in[1];
    const float* Wb   = (const float*)d_in[2];
    const float* W1   = (const float*)d_in[3];
    const float* W1b  = (const float*)d_in[4];
    const float* W2   = (const float*)d_in[5];
    const float* W2b  = (const float*)d_in[6];
    const float* mWih = (const float*)d_in[7];
    const float* mWhh = (const float*)d_in[8];
    const float* mbih = (const float*)d_in[9];
    const float* mbhh = (const float*)d_in[10];
    const float* aWih = (const float*)d_in[11];
    const float* aWhh = (const float*)d_in[12];
    const float* abih = (const float*)d_in[13];
    const float* abhh = (const float*)d_in[14];

    char* p = (char*)d_ws;
    auto nb = [&](size_t bytes) -> char* {
        char* r = p; p += (bytes + 255) & ~(size_t)255; return r;
    };
    u16* W1p     = (u16*)nb(1024ull * 9216 * 2);   // 18 MiB
    u16* Wb_bf   = (u16*)nb(1024ull * 1024 * 2);
    u16* W2_bf   = (u16*)nb(1024ull * 1024 * 2);
    u16* aWih_bf = (u16*)nb(3072ull * 1024 * 2);
    u16* aWhh_bf = (u16*)nb(3072ull * 1024 * 2);
    u16* mWih_bf = (u16*)nb(3072ull * 1024 * 2);
    u16* mWhh_bf = (u16*)nb(3072ull * 1024 * 2);
    u16* qbf     = (u16*)nb(64 * 1024 * 2);
    u16* m1bf    = (u16*)nb(64 * 1024 * 2);
    u16* m2bf    = (u16*)nb(64 * 1024 * 2);
    u16* hA      = (u16*)nb(64 * 1024 * 2);
    u16* hB      = (u16*)nb(64 * 1024 * 2);
    u16* Zq      = (u16*)nb(8192ull * 4096 * 2);   // 64 MiB (Zm aliases)
    u16* GIb     = (u16*)nb(8192ull * 3072 * 2);   // 48 MiB
    u16* G1      = (u16*)nb(8192ull * 1024 * 2);   // 16 MiB
    u16* G       = (u16*)nb(8192ull * 1024 * 2);   // 16 MiB
    float* P0    = (float*)nb(8192ull * 1024 * 4); // 32 MiB
    float* Wbq   = (float*)nb(64 * 1024 * 4);
    float* Wbm   = (float*)nb(64 * 1024 * 4);
    float* addq  = (float*)nb(64 * 1024 * 4);
    float* addt  = (float*)nb(64 * 1024 * 4);
    float* m1    = (float*)nb(64 * 1024 * 4);
    unsigned* slots = (unsigned*)nb(1088 * 4 + 256);  // 64x16 arrival + go
    u16* Zm      = Zq;  // alias: Zq dead once episode-0 G1 GEMM completes

    size_t needed = (size_t)(p - (char*)d_ws);
    if (needed > ws_size) {
        fill_sentinel<<<256, 256, 0, stream>>>((float*)d_out, out_size, 12345.0f);
        return;
    }

    // allow >64 KiB dynamic LDS for the persistent kernel (idempotent)
    static bool attr_set = false;
    const int ws_lds = 48 * 1032 * 2;  // 99072 B
    if (!attr_set) {
        (void)hipFuncSetAttribute((const void*)gru_persist,
                                  hipFuncAttributeMaxDynamicSharedMemorySize, ws_lds);
        attr_set = true;
    }

    // weight converts
    conv_bf<<<256, 256, 0, stream>>>(q, qbf, 64 * 1024);
    conv_bf<<<2048, 256, 0, stream>>>(Wb, Wb_bf, 1024 * 1024);
    conv_bf<<<2048, 256, 0, stream>>>(W2, W2_bf, 1024 * 1024);
    conv_bf<<<4096, 256, 0, stream>>>(aWih, aWih_bf, 3072 * 1024);
    conv_bf<<<4096, 256, 0, stream>>>(aWhh, aWhh_bf, 3072 * 1024);
    conv_bf<<<4096, 256, 0, stream>>>(mWih, mWih_bf, 3072 * 1024);
    conv_bf<<<4096, 256, 0, stream>>>(mWhh, mWhh_bf, 3072 * 1024);
    repack_w1<<<8192, 256, 0, stream>>>(W1, W1p);

    // episode-invariant precompute
    gemm_bt<0><<<dim3(8, 1), 256, 0, stream>>>(qbf, 1024, Wb_bf, 1024, Wbq, 64, 1024, 1024,
                                               nullptr, nullptr, nullptr);
    gemm_bt<1><<<dim3(8, 1), 256, 0, stream>>>(qbf, 1024, W1p + 8192, 9216, addq, 64, 1024, 1024,
                                               W1b, nullptr, nullptr);
    build_zq<<<16384, 256, 0, stream>>>(c, q, Wbq, Zq);
    gemm_bt<0><<<dim3(8, 64), 256, 0, stream>>>(Zq, 4096, W1p, 9216, P0, 8192, 1024, 4096,
                                                nullptr, nullptr, nullptr);
    gemm_bt<2><<<dim3(24, 64), 256, 0, stream>>>(Zq, 4096, aWih_bf, 1024, GIb, 8192, 3072, 1024,
                                                 abih, nullptr, nullptr);

    for (int ep = 0; ep < 2; ep++) {
        const u16* mbf_cur = ep ? m1bf : qbf;
        const float* mold  = ep ? (const float*)m1 : q;
        // addterm = m@W1_blk1 + (q@W1_blk2 + b1)
        gemm_bt<3><<<dim3(8, 1), 256, 0, stream>>>(mbf_cur, 1024, W1p + 7168, 9216, addt,
                                                   64, 1024, 1024, nullptr, addq, nullptr);
        const u16* AG1; int ldaG1;
        if (ep) {
            gemm_bt<0><<<dim3(8, 1), 256, 0, stream>>>(m1bf, 1024, Wb_bf, 1024, Wbm,
                                                       64, 1024, 1024, nullptr, nullptr, nullptr);
            build_zm<<<16384, 256, 0, stream>>>(c, m1, Wbm, Zm);
            AG1 = Zm; ldaG1 = 3072;
        } else {
            AG1 = Zq + 1024; ldaG1 = 4096;  // m==q: reuse invariant features
        }
        gemm_bt<4><<<dim3(8, 64), 256, 0, stream>>>(AG1, ldaG1, W1p + 4096, 9216, G1,
                                                    8192, 1024, 3072, nullptr, P0, addt);
        gemm_bt<5><<<dim3(8, 64), 256, 0, stream>>>(G1, 1024, W2_bf, 1024, G,
                                                    8192, 1024, 1024, W2b, nullptr, nullptr);

        // persistent 128-step episode
        zero_state<<<64, 256, 0, stream>>>(hA, slots, 64 * 1024);
        gru_persist<<<64, 256, ws_lds, stream>>>(aWhh_bf, abhh, GIb, G, hA, hB, slots);

        // 128 steps (t=127 writes hA) -> final h in hA
        float* mo = ep ? (float*)d_out : m1;
        u16* mob = ep ? m2bf : m1bf;
        gru_mem<<<16, 256, 0, stream>>>(hA, mbf_cur, mold, mWih_bf, mWhh_bf,
                                        mbih, mbhh, mo, mob);
    }
}

// Round 5
// 2872.939 us; speedup vs baseline: 3.2940x; 1.5250x over previous
//
#include <hip/hip_runtime.h>

// ---------------------------------------------------------------------------
// EpisodicMemoryModule: T=128, B=64, D=1024, 2 episodes.
//   - Feature GEMM z@W1^T split into 9 K-blocks; invariants hoisted (P0, K=4096),
//     per-episode blocks (K=3072), rank-64 terms folded into epilogue.
//   - Episode 0 reuses invariant features (m == q).
//   - att-GRU input gi = c@Wih^T batched over all t (GI, M=8192).
//   - Serial part: persistent kernel, 64 blocks x 16-d slice, Whh in LDS.
//     h exchanged via RELAXED system-scope atomics (LLC-point, bypass L1/L2).
//     Barrier: per-block padded slots + block-0 gather + go flag, ALL RELAXED
//     (no acquire/release -> no per-poll buffer_inv / wbl2 cache storms;
//     ordering via the vmcnt(0) drain __syncthreads provides).
//     h staged through LDS in K=256 chunks (coalesced loads + ds_write_b128).
// ---------------------------------------------------------------------------

typedef unsigned short u16;
typedef unsigned long long u64;
typedef __attribute__((ext_vector_type(8))) short bf16x8;
typedef __attribute__((ext_vector_type(8))) unsigned short u16x8;
typedef __attribute__((ext_vector_type(4))) float f32x4;

__device__ inline float bf2f(u16 u) {
    union { unsigned u; float f; } v; v.u = ((unsigned)u) << 16; return v.f;
}
__device__ inline u16 f2bf(float f) {
    union { float f; unsigned u; } v; v.f = f;
    unsigned r = v.u + 0x7fff + ((v.u >> 16) & 1);
    return (u16)(r >> 16);
}
__device__ inline float sigf(float x) { return 1.f / (1.f + expf(-x)); }

__device__ inline u64 cload64(const u16* p) {
    return __hip_atomic_load((const u64*)p, __ATOMIC_RELAXED, __HIP_MEMORY_SCOPE_SYSTEM);
}
__device__ inline void cstore64(u16* p, u64 v) {
    __hip_atomic_store((u64*)p, v, __ATOMIC_RELAXED, __HIP_MEMORY_SCOPE_SYSTEM);
}

__global__ void fill_sentinel(float* __restrict__ d, int n, float v) {
    for (int i = blockIdx.x * 256 + threadIdx.x; i < n; i += gridDim.x * 256) d[i] = v;
}

// zero h state (via LLC-point stores so no stale L2 copy exists) + barrier slots
__global__ void zero_state(u16* __restrict__ hb, unsigned* __restrict__ slots, int n) {
    int i = blockIdx.x * 256 + threadIdx.x;
    for (int j = i; j < n / 4; j += gridDim.x * 256)
        __hip_atomic_store((u64*)hb + j, 0ull, __ATOMIC_RELAXED, __HIP_MEMORY_SCOPE_SYSTEM);
    if (i < 1088)
        __hip_atomic_store(slots + i, 0u, __ATOMIC_RELAXED, __HIP_MEMORY_SCOPE_SYSTEM);
}

// ---------------- elementwise converts ----------------
__global__ void conv_bf(const float* __restrict__ s, u16* __restrict__ d, int n) {
    for (int i = blockIdx.x * 256 + threadIdx.x; i < n; i += gridDim.x * 256)
        d[i] = f2bf(s[i]);
}

// Repack W1 [1024][9216] -> bf16 with K-block order {0,3,5,7, 4,6,8, 1, 2}
__global__ void repack_w1(const float* __restrict__ W1, u16* __restrict__ out) {
    const int jmap[9] = {0, 3, 5, 7, 4, 6, 8, 1, 2};
    const int total = 1024 * 9216;
    for (int i = blockIdx.x * 256 + threadIdx.x; i < total; i += gridDim.x * 256) {
        int n = i / 9216;
        int rest = i - n * 9216;
        int v = rest >> 10, k = rest & 1023;
        out[(size_t)n * 9216 + rest] = f2bf(W1[(size_t)n * 9216 + jmap[v] * 1024 + k]);
    }
}

// Zq[(t*64+b)][4096] = bf16{ c, c*q, |c-q|, c*Wbq }
__global__ void build_zq(const float* __restrict__ c, const float* __restrict__ q,
                         const float* __restrict__ wbq, u16* __restrict__ Zq) {
    const int total = 8192 * 1024;
    for (int i = blockIdx.x * 256 + threadIdx.x; i < total; i += gridDim.x * 256) {
        int row = i >> 10, k = i & 1023, b = row & 63;
        float cv = c[i];
        float qv = q[b * 1024 + k];
        float wv = wbq[b * 1024 + k];
        size_t ro = (size_t)row * 4096;
        Zq[ro + k]        = f2bf(cv);
        Zq[ro + 1024 + k] = f2bf(cv * qv);
        Zq[ro + 2048 + k] = f2bf(fabsf(cv - qv));
        Zq[ro + 3072 + k] = f2bf(cv * wv);
    }
}

// Zm[(t*64+b)][3072] = bf16{ c*m, |c-m|, c*Wbm }
__global__ void build_zm(const float* __restrict__ c, const float* __restrict__ m,
                         const float* __restrict__ wbm, u16* __restrict__ Zm) {
    const int total = 8192 * 1024;
    for (int i = blockIdx.x * 256 + threadIdx.x; i < total; i += gridDim.x * 256) {
        int row = i >> 10, k = i & 1023, b = row & 63;
        float cv = c[i];
        float mv = m[b * 1024 + k];
        float wv = wbm[b * 1024 + k];
        size_t ro = (size_t)row * 3072;
        Zm[ro + k]        = f2bf(cv * mv);
        Zm[ro + 1024 + k] = f2bf(fabsf(cv - mv));
        Zm[ro + 2048 + k] = f2bf(cv * wv);
    }
}

// ---------------- generic C = A @ B^T GEMM (bf16 in, fp32 acc) ----------------
// MODE 0: fp32 out           1: fp32 out + bias[n]       2: bf16 out + bias[n]
//      3: fp32 out + prevf[m][n]
//      4: bf16 out = tanh(acc + prevf[m][n] + addb[m&63][n])
//      5: bf16 out = sigmoid(acc + bias[n])
template <int MODE>
__global__ __launch_bounds__(256) void gemm_bt(
    const u16* __restrict__ A, int lda,
    const u16* __restrict__ B, int ldb,
    void* __restrict__ C, int M, int N, int K,
    const float* __restrict__ bias,
    const float* __restrict__ prevf,
    const float* __restrict__ addb) {
    __shared__ u16 As[128 * 40];
    __shared__ u16 Bs[128 * 40];
    const int t = threadIdx.x;
    const int bn = blockIdx.x, bm = blockIdx.y;
    const int w = t >> 6, lane = t & 63, lr = lane & 15, quad = lane >> 4;
    const int wm = (w >> 1) * 64, wn = (w & 1) * 64;
    const int r0 = t >> 2, kb = (t & 3) * 8;

    f32x4 zero4 = {0.f, 0.f, 0.f, 0.f};
    f32x4 acc[4][4];
#pragma unroll
    for (int i = 0; i < 4; i++)
#pragma unroll
        for (int j = 0; j < 4; j++) acc[i][j] = zero4;

    const u16x8 zz = {0, 0, 0, 0, 0, 0, 0, 0};

    for (int k0 = 0; k0 < K; k0 += 32) {
#pragma unroll
        for (int rr = r0; rr < 128; rr += 64) {
            int gm = bm * 128 + rr;
            u16x8 av = zz;
            if (gm < M) av = *(const u16x8*)(A + (size_t)gm * lda + k0 + kb);
            *(u16x8*)(As + rr * 40 + kb) = av;
            int gn = bn * 128 + rr;
            *(u16x8*)(Bs + rr * 40 + kb) = *(const u16x8*)(B + (size_t)gn * ldb + k0 + kb);
        }
        __syncthreads();
        bf16x8 af[4], bfr[4];
#pragma unroll
        for (int i = 0; i < 4; i++) af[i] = *(const bf16x8*)(As + (wm + i * 16 + lr) * 40 + quad * 8);
#pragma unroll
        for (int j = 0; j < 4; j++) bfr[j] = *(const bf16x8*)(Bs + (wn + j * 16 + lr) * 40 + quad * 8);
#pragma unroll
        for (int i = 0; i < 4; i++)
#pragma unroll
            for (int j = 0; j < 4; j++)
                acc[i][j] = __builtin_amdgcn_mfma_f32_16x16x32_bf16(af[i], bfr[j], acc[i][j], 0, 0, 0);
        __syncthreads();
    }

#pragma unroll
    for (int i = 0; i < 4; i++) {
        int gm0 = bm * 128 + wm + i * 16 + quad * 4;
#pragma unroll
        for (int j = 0; j < 4; j++) {
            int gn = bn * 128 + wn + j * 16 + lr;
#pragma unroll
            for (int reg = 0; reg < 4; reg++) {
                int gm = gm0 + reg;
                if (gm >= M) continue;
                float v = acc[i][j][reg];
                size_t o = (size_t)gm * N + gn;
                if constexpr (MODE == 0) ((float*)C)[o] = v;
                else if constexpr (MODE == 1) ((float*)C)[o] = v + bias[gn];
                else if constexpr (MODE == 2) ((u16*)C)[o] = f2bf(v + bias[gn]);
                else if constexpr (MODE == 3) ((float*)C)[o] = v + prevf[o];
                else if constexpr (MODE == 4)
                    ((u16*)C)[o] = f2bf(tanhf(v + prevf[o] + addb[(size_t)(gm & 63) * N + gn]));
                else if constexpr (MODE == 5) ((u16*)C)[o] = f2bf(sigf(v + bias[gn]));
            }
        }
    }
}

// ---------------- persistent attention-GRU episode kernel ----------------
// 64 blocks; block owns d-slice [ds, ds+16).
// LDS: Ws = Whh A-slice (48 rows x 1024, stride 1032)  +  hchunk (64 rows x
// 256 k, stride 264) staged per K-chunk.
// MFMA roles: A = Whh rows (d), B = h rows (b) -> lane owns
// (b = w*16 + (lane&15), d = ds + quad*4 + reg).
// All cross-block traffic (h, flags) is RELAXED system-scope (LLC-point);
// no acquire/release -> zero cache-maintenance instructions per step.
__global__ __launch_bounds__(256, 1) void gru_persist(
    const u16* __restrict__ Whh, const float* __restrict__ bhh,
    const u16* __restrict__ GIb, const u16* __restrict__ G,
    u16* __restrict__ hA, u16* __restrict__ hB,
    unsigned* __restrict__ slots) {
    extern __shared__ u16 Ws[];           // [48*1032] then hchunk [64*264]
    u16* hch = Ws + 48 * 1032;
    unsigned* goflag = slots + 1024;      // slots: 64 x 16 u32 padded; go at +1024
    const int tid = threadIdx.x;
    const int bid = blockIdx.x;
    const int ds = bid * 16;
    const int w = tid >> 6, lane = tid & 63, lr = lane & 15, quad = lane >> 4;

    // stage Whh A-slice once: row r = g*16 + dl -> Whh[g*1024 + ds + dl][:]
    for (int idx = tid; idx < 48 * 128; idx += 256) {
        int r = idx >> 7, col8 = (idx & 127) * 8;
        int g = r >> 4, dl = r & 15;
        *(u16x8*)(Ws + r * 1032 + col8) =
            *(const u16x8*)(Whh + (size_t)(g * 1024 + ds + dl) * 1024 + col8);
    }

    const int b = w * 16 + lr;         // lane's batch row (B-frag n, C col)
    const int d0 = ds + quad * 4;      // lane's first d (C rows quad*4+reg)
    f32x4 bhr4 = *(const f32x4*)(bhh + d0);
    f32x4 bhz4 = *(const f32x4*)(bhh + 1024 + d0);
    f32x4 bhn4 = *(const f32x4*)(bhh + 2048 + d0);
    f32x4 h = {0.f, 0.f, 0.f, 0.f};

    const u16* wsA = Ws + lr * 1032 + quad * 8;       // A-frag base (gate 0)
    const u16* hrd = hch + (w * 16 + lr) * 264 + quad * 8;  // B-frag base

    // h-chunk load mapping: 16B unit u = l*256 + tid, l=0..7;
    // row = u>>5, colu = u&31 (32 x 16B per 256-k row)
    const int lrow[2] = {tid >> 5, (256 + tid) >> 5};  // rows for l even/odd pattern
    __syncthreads();

    for (int t = 0; t < 128; t++) {
        const u16* hin = (t & 1) ? hB : hA;
        u16* hout = (t & 1) ? hA : hB;

        // step operands (independent of h; overlap with h staging)
        const u16* GIt = GIb + (size_t)t * 196608;
        const u16* Gt = G + (size_t)t * 65536;
        u64 pgir = *(const u64*)(GIt + b * 3072 + d0);
        u64 pgiz = *(const u64*)(GIt + b * 3072 + 1024 + d0);
        u64 pgin = *(const u64*)(GIt + b * 3072 + 2048 + d0);
        u64 pgg  = *(const u64*)(Gt + b * 1024 + d0);

        f32x4 accr = {0.f, 0.f, 0.f, 0.f}, accz = accr, accn = accr;

        // prefetch chunk 0
        u64 pf[16];
#pragma unroll
        for (int l = 0; l < 8; l++) {
            int u = l * 256 + tid;
            const u16* gp = hin + (u >> 5) * 1024 + (u & 31) * 8;
            pf[2 * l] = cload64(gp);
            pf[2 * l + 1] = cload64(gp + 4);
        }

        for (int c = 0; c < 4; c++) {
            __syncthreads();  // previous chunk's ds_reads done
#pragma unroll
            for (int l = 0; l < 8; l++) {
                int u = l * 256 + tid;
                union { u64 q[2]; u16x8 v; } pv;
                pv.q[0] = pf[2 * l]; pv.q[1] = pf[2 * l + 1];
                *(u16x8*)(hch + (u >> 5) * 264 + (u & 31) * 8) = pv.v;
            }
            __syncthreads();
            if (c < 3) {  // prefetch next chunk; overlaps MFMAs below
#pragma unroll
                for (int l = 0; l < 8; l++) {
                    int u = l * 256 + tid;
                    const u16* gp = hin + (u >> 5) * 1024 + (c + 1) * 256 + (u & 31) * 8;
                    pf[2 * l] = cload64(gp);
                    pf[2 * l + 1] = cload64(gp + 4);
                }
            }
#pragma unroll
            for (int ki = 0; ki < 8; ki++) {
                int kl = ki * 32;                 // chunk-local k
                int kg = c * 256 + kl;            // global k
                bf16x8 bv = *(const bf16x8*)(hrd + kl);
                bf16x8 a_r = *(const bf16x8*)(wsA + kg);
                bf16x8 a_z = *(const bf16x8*)(wsA + 16 * 1032 + kg);
                bf16x8 a_n = *(const bf16x8*)(wsA + 32 * 1032 + kg);
                accr = __builtin_amdgcn_mfma_f32_16x16x32_bf16(a_r, bv, accr, 0, 0, 0);
                accz = __builtin_amdgcn_mfma_f32_16x16x32_bf16(a_z, bv, accz, 0, 0, 0);
                accn = __builtin_amdgcn_mfma_f32_16x16x32_bf16(a_n, bv, accn, 0, 0, 0);
            }
        }

        // gate math on register h state; one 64-bit LLC store
        u64 outv = 0;
#pragma unroll
        for (int reg = 0; reg < 4; reg++) {
            float r = sigf(bf2f((u16)(pgir >> (16 * reg))) + accr[reg] + bhr4[reg]);
            float z = sigf(bf2f((u16)(pgiz >> (16 * reg))) + accz[reg] + bhz4[reg]);
            float n = tanhf(bf2f((u16)(pgin >> (16 * reg))) + r * (accn[reg] + bhn4[reg]));
            float hatt = (1.f - z) * n + z * h[reg];
            float g = bf2f((u16)(pgg >> (16 * reg)));
            h[reg] = g * hatt + (1.f - g) * h[reg];
            outv |= (u64)f2bf(h[reg]) << (16 * reg);
        }
        cstore64(hout + b * 1024 + d0, outv);

        if (t == 127) break;  // no barrier after the last step

        // ---- flush-free two-level grid barrier, epoch = t+1 ----
        // __syncthreads drains vmcnt(0): h stores are ACKed at LLC before the
        // slot store issues; consumer h loads issue only after observing the
        // flag -> LLC already holds fresh h. No acquire/release needed.
        unsigned epoch = (unsigned)(t + 1);
        __syncthreads();
        if (tid == 0)
            __hip_atomic_store(slots + bid * 16, epoch, __ATOMIC_RELAXED,
                               __HIP_MEMORY_SCOPE_SYSTEM);
        if (bid == 0) {
            if (tid < 64) {
                while (__hip_atomic_load(slots + tid * 16, __ATOMIC_RELAXED,
                                         __HIP_MEMORY_SCOPE_SYSTEM) < epoch)
                    __builtin_amdgcn_s_sleep(1);
            }
            __syncthreads();
            if (tid == 0)
                __hip_atomic_store(goflag, epoch, __ATOMIC_RELAXED,
                                   __HIP_MEMORY_SCOPE_SYSTEM);
        }
        if (tid == 0) {
            while (__hip_atomic_load(goflag, __ATOMIC_RELAXED,
                                     __HIP_MEMORY_SCOPE_SYSTEM) < epoch)
                __builtin_amdgcn_s_sleep(1);
        }
        __syncthreads();
    }
}

// ---------------- mem GRU cell: m' = GRUCell(e, m) ----------------
__global__ __launch_bounds__(256) void gru_mem(
    const u16* __restrict__ ebf, const u16* __restrict__ mbf,
    const float* __restrict__ mold,
    const u16* __restrict__ Wih, const u16* __restrict__ Whh,
    const float* __restrict__ bih, const float* __restrict__ bhh,
    float* __restrict__ mout, u16* __restrict__ mbf_out) {
    __shared__ u16 es[64 * 40];
    __shared__ u16 ms[64 * 40];
    __shared__ u16 Wi[192 * 40];
    __shared__ u16 Wh[192 * 40];
    const int t = threadIdx.x;
    const int ds = blockIdx.x * 64;
    const int w = t >> 6, lane = t & 63, lr = lane & 15, quad = lane >> 4;
    const int r0 = t >> 2, kb = (t & 3) * 8;

    f32x4 zero4 = {0.f, 0.f, 0.f, 0.f};
    f32x4 ai[4][3], ah[4][3];
#pragma unroll
    for (int i = 0; i < 4; i++)
#pragma unroll
        for (int g = 0; g < 3; g++) { ai[i][g] = zero4; ah[i][g] = zero4; }

    for (int k0 = 0; k0 < 1024; k0 += 32) {
        // e (final h) was written via LLC-point stores -> read coherently
        union { u64 q[2]; u16x8 v; } eu;
        eu.q[0] = cload64(ebf + r0 * 1024 + k0 + kb);
        eu.q[1] = cload64(ebf + r0 * 1024 + k0 + kb + 4);
        *(u16x8*)(es + r0 * 40 + kb) = eu.v;
        *(u16x8*)(ms + r0 * 40 + kb) = *(const u16x8*)(mbf + r0 * 1024 + k0 + kb);
#pragma unroll
        for (int ln = r0; ln < 192; ln += 64) {
            int g = ln >> 6, dl = ln & 63;
            size_t ro = (size_t)(g * 1024 + ds + dl) * 1024 + k0 + kb;
            *(u16x8*)(Wi + ln * 40 + kb) = *(const u16x8*)(Wih + ro);
            *(u16x8*)(Wh + ln * 40 + kb) = *(const u16x8*)(Whh + ro);
        }
        __syncthreads();
        bf16x8 ae[4], am[4], bi[3], bh[3];
#pragma unroll
        for (int i = 0; i < 4; i++) {
            ae[i] = *(const bf16x8*)(es + (i * 16 + lr) * 40 + quad * 8);
            am[i] = *(const bf16x8*)(ms + (i * 16 + lr) * 40 + quad * 8);
        }
#pragma unroll
        for (int g = 0; g < 3; g++) {
            bi[g] = *(const bf16x8*)(Wi + (g * 64 + w * 16 + lr) * 40 + quad * 8);
            bh[g] = *(const bf16x8*)(Wh + (g * 64 + w * 16 + lr) * 40 + quad * 8);
        }
#pragma unroll
        for (int i = 0; i < 4; i++)
#pragma unroll
            for (int g = 0; g < 3; g++) {
                ai[i][g] = __builtin_amdgcn_mfma_f32_16x16x32_bf16(ae[i], bi[g], ai[i][g], 0, 0, 0);
                ah[i][g] = __builtin_amdgcn_mfma_f32_16x16x32_bf16(am[i], bh[g], ah[i][g], 0, 0, 0);
            }
        __syncthreads();
    }

    const int d = ds + w * 16 + lr;
    const float bir = bih[d], biz = bih[1024 + d], bin = bih[2048 + d];
    const float bhr = bhh[d], bhz = bhh[1024 + d], bhn = bhh[2048 + d];
#pragma unroll
    for (int i = 0; i < 4; i++) {
#pragma unroll
        for (int reg = 0; reg < 4; reg++) {
            int b = i * 16 + quad * 4 + reg;
            float r = sigf(ai[i][0][reg] + bir + ah[i][0][reg] + bhr);
            float z = sigf(ai[i][1][reg] + biz + ah[i][1][reg] + bhz);
            float n = tanhf(ai[i][2][reg] + bin + r * (ah[i][2][reg] + bhn));
            float mo = mold[b * 1024 + d];
            float mn = (1.f - z) * n + z * mo;
            mout[b * 1024 + d] = mn;
            mbf_out[b * 1024 + d] = f2bf(mn);
        }
    }
}

// ---------------------------------------------------------------------------
extern "C" void kernel_launch(void* const* d_in, const int* in_sizes, int n_in,
                              void* d_out, int out_size, void* d_ws, size_t ws_size,
                              hipStream_t stream) {
    const float* c    = (const float*)d_in[0];
    const float* q    = (const float*)d_in[1];
    const float* Wb   = (const float*)d_in[2];
    const float* W1   = (const float*)d_in[3];
    const float* W1b  = (const float*)d_in[4];
    const float* W2   = (const float*)d_in[5];
    const float* W2b  = (const float*)d_in[6];
    const float* mWih = (const float*)d_in[7];
    const float* mWhh = (const float*)d_in[8];
    const float* mbih = (const float*)d_in[9];
    const float* mbhh = (const float*)d_in[10];
    const float* aWih = (const float*)d_in[11];
    const float* aWhh = (const float*)d_in[12];
    const float* abih = (const float*)d_in[13];
    const float* abhh = (const float*)d_in[14];

    char* p = (char*)d_ws;
    auto nb = [&](size_t bytes) -> char* {
        char* r = p; p += (bytes + 255) & ~(size_t)255; return r;
    };
    u16* W1p     = (u16*)nb(1024ull * 9216 * 2);   // 18 MiB
    u16* Wb_bf   = (u16*)nb(1024ull * 1024 * 2);
    u16* W2_bf   = (u16*)nb(1024ull * 1024 * 2);
    u16* aWih_bf = (u16*)nb(3072ull * 1024 * 2);
    u16* aWhh_bf = (u16*)nb(3072ull * 1024 * 2);
    u16* mWih_bf = (u16*)nb(3072ull * 1024 * 2);
    u16* mWhh_bf = (u16*)nb(3072ull * 1024 * 2);
    u16* qbf     = (u16*)nb(64 * 1024 * 2);
    u16* m1bf    = (u16*)nb(64 * 1024 * 2);
    u16* m2bf    = (u16*)nb(64 * 1024 * 2);
    u16* hA      = (u16*)nb(64 * 1024 * 2);
    u16* hB      = (u16*)nb(64 * 1024 * 2);
    u16* Zq      = (u16*)nb(8192ull * 4096 * 2);   // 64 MiB (Zm aliases)
    u16* GIb     = (u16*)nb(8192ull * 3072 * 2);   // 48 MiB
    u16* G1      = (u16*)nb(8192ull * 1024 * 2);   // 16 MiB
    u16* G       = (u16*)nb(8192ull * 1024 * 2);   // 16 MiB
    float* P0    = (float*)nb(8192ull * 1024 * 4); // 32 MiB
    float* Wbq   = (float*)nb(64 * 1024 * 4);
    float* Wbm   = (float*)nb(64 * 1024 * 4);
    float* addq  = (float*)nb(64 * 1024 * 4);
    float* addt  = (float*)nb(64 * 1024 * 4);
    float* m1    = (float*)nb(64 * 1024 * 4);
    unsigned* slots = (unsigned*)nb(1088 * 4 + 256);  // 64x16 arrival + go
    u16* Zm      = Zq;  // alias: Zq dead once episode-0 G1 GEMM completes

    size_t needed = (size_t)(p - (char*)d_ws);
    if (needed > ws_size) {
        fill_sentinel<<<256, 256, 0, stream>>>((float*)d_out, out_size, 12345.0f);
        return;
    }

    // allow >64 KiB dynamic LDS for the persistent kernel (idempotent)
    static bool attr_set = false;
    const int ws_lds = (48 * 1032 + 64 * 264) * 2;  // 132864 B
    if (!attr_set) {
        (void)hipFuncSetAttribute((const void*)gru_persist,
                                  hipFuncAttributeMaxDynamicSharedMemorySize, ws_lds);
        attr_set = true;
    }

    // weight converts
    conv_bf<<<256, 256, 0, stream>>>(q, qbf, 64 * 1024);
    conv_bf<<<2048, 256, 0, stream>>>(Wb, Wb_bf, 1024 * 1024);
    conv_bf<<<2048, 256, 0, stream>>>(W2, W2_bf, 1024 * 1024);
    conv_bf<<<4096, 256, 0, stream>>>(aWih, aWih_bf, 3072 * 1024);
    conv_bf<<<4096, 256, 0, stream>>>(aWhh, aWhh_bf, 3072 * 1024);
    conv_bf<<<4096, 256, 0, stream>>>(mWih, mWih_bf, 3072 * 1024);
    conv_bf<<<4096, 256, 0, stream>>>(mWhh, mWhh_bf, 3072 * 1024);
    repack_w1<<<8192, 256, 0, stream>>>(W1, W1p);

    // episode-invariant precompute
    gemm_bt<0><<<dim3(8, 1), 256, 0, stream>>>(qbf, 1024, Wb_bf, 1024, Wbq, 64, 1024, 1024,
                                               nullptr, nullptr, nullptr);
    gemm_bt<1><<<dim3(8, 1), 256, 0, stream>>>(qbf, 1024, W1p + 8192, 9216, addq, 64, 1024, 1024,
                                               W1b, nullptr, nullptr);
    build_zq<<<16384, 256, 0, stream>>>(c, q, Wbq, Zq);
    gemm_bt<0><<<dim3(8, 64), 256, 0, stream>>>(Zq, 4096, W1p, 9216, P0, 8192, 1024, 4096,
                                                nullptr, nullptr, nullptr);
    gemm_bt<2><<<dim3(24, 64), 256, 0, stream>>>(Zq, 4096, aWih_bf, 1024, GIb, 8192, 3072, 1024,
                                                 abih, nullptr, nullptr);

    for (int ep = 0; ep < 2; ep++) {
        const u16* mbf_cur = ep ? m1bf : qbf;
        const float* mold  = ep ? (const float*)m1 : q;
        // addterm = m@W1_blk1 + (q@W1_blk2 + b1)
        gemm_bt<3><<<dim3(8, 1), 256, 0, stream>>>(mbf_cur, 1024, W1p + 7168, 9216, addt,
                                                   64, 1024, 1024, nullptr, addq, nullptr);
        const u16* AG1; int ldaG1;
        if (ep) {
            gemm_bt<0><<<dim3(8, 1), 256, 0, stream>>>(m1bf, 1024, Wb_bf, 1024, Wbm,
                                                       64, 1024, 1024, nullptr, nullptr, nullptr);
            build_zm<<<16384, 256, 0, stream>>>(c, m1, Wbm, Zm);
            AG1 = Zm; ldaG1 = 3072;
        } else {
            AG1 = Zq + 1024; ldaG1 = 4096;  // m==q: reuse invariant features
        }
        gemm_bt<4><<<dim3(8, 64), 256, 0, stream>>>(AG1, ldaG1, W1p + 4096, 9216, G1,
                                                    8192, 1024, 3072, nullptr, P0, addt);
        gemm_bt<5><<<dim3(8, 64), 256, 0, stream>>>(G1, 1024, W2_bf, 1024, G,
                                                    8192, 1024, 1024, W2b, nullptr, nullptr);

        // persistent 128-step episode
        zero_state<<<64, 256, 0, stream>>>(hA, slots, 64 * 1024);
        gru_persist<<<64, 256, ws_lds, stream>>>(aWhh_bf, abhh, GIb, G, hA, hB, slots);

        // 128 steps (t=127 writes hA) -> final h in hA
        float* mo = ep ? (float*)d_out : m1;
        u16* mob = ep ? m2bf : m1bf;
        gru_mem<<<16, 256, 0, stream>>>(hA, mbf_cur, mold, mWih_bf, mWhh_bf,
                                        mbih, mbhh, mo, mob);
    }
}